// Round 3
// baseline (227.994 us; speedup 1.0000x reference)
//
#include <hip/hip_runtime.h>
#include <math.h>

typedef short bf16x8 __attribute__((ext_vector_type(8)));
typedef float f32x4  __attribute__((ext_vector_type(4)));

// round-to-nearest-even float -> bf16 bits
__device__ __forceinline__ unsigned short f2bf(float x) {
    unsigned int u = __float_as_uint(x);
    return (unsigned short)((u + 0x7FFFu + ((u >> 16) & 1u)) >> 16);
}
__device__ __forceinline__ float bf2f(unsigned short h) {
    return __uint_as_float(((unsigned int)h) << 16);
}
// RNE split (precompute path)
__device__ __forceinline__ void split2(float x, unsigned short& h, unsigned short& l) {
    h = f2bf(x);
    l = f2bf(x - bf2f(h));
}
// truncation split (hot path): hi = trunc(x), lo = RNE(x-hi); combined rel err ~2^-17
__device__ __forceinline__ void split2t(float x, unsigned short& h, unsigned short& l) {
    unsigned int u = __float_as_uint(x);
    h = (unsigned short)(u >> 16);
    float r = x - __uint_as_float(u & 0xFFFF0000u);
    l = f2bf(r);
}

// XOR-swizzled H index within a 16-row wave-private strip (shorts, stride 64).
// Bank analysis: row stride = 32 dwords == 0 mod 32 banks, so bank is set by
// the 16B chunk; chunk' = chunk ^ (row&7) spreads the 16 rows of a b128
// column read across all 8 chunks = 32 banks (measured 688K conflicts with
// this family of swizzles vs 3.05M padded — r13/r14).
__device__ __forceinline__ int hsw16(int row, int col) {
    return (row << 6) + ((((col >> 3) ^ (row & 7)) << 3) | (col & 7));
}

__device__ __forceinline__ float inv_norm3(float x, float y, float z) {
    float d = fmaf(x, x, fmaf(y, y, z * z));
    return rsqrtf(fmaxf(d, 1e-24f));
}
__device__ __forceinline__ float3 f3sub(float3 a, float3 b) {
    return make_float3(a.x - b.x, a.y - b.y, a.z - b.z);
}
__device__ __forceinline__ float3 f3cross(float3 a, float3 b) {
    return make_float3(a.y * b.z - a.z * b.y,
                       a.z * b.x - a.x * b.z,
                       a.x * b.y - a.y * b.x);
}
// NeRF frame, parallel normalizations (n from unnormalized w: same direction)
__device__ __forceinline__ void nerf_frame(const float3& A, const float3& Bv,
                                           const float3& C, float3& bc,
                                           float3& n, float3& m3) {
    float3 w  = f3sub(C, Bv);
    float3 v  = f3sub(Bv, A);
    float3 cr = f3cross(v, w);
    float iw = inv_norm3(w.x, w.y, w.z);
    float ic = inv_norm3(cr.x, cr.y, cr.z);
    bc = make_float3(w.x * iw, w.y * iw, w.z * iw);
    n  = make_float3(cr.x * ic, cr.y * ic, cr.z * ic);
    m3 = f3cross(n, bc);
}
__device__ __forceinline__ float3 nerf_place(const float3& C, const float3& bc,
                                             const float3& m3, const float3& n,
                                             float tx, float ty, float tz) {
    return make_float3(
        fmaf(m3.x, ty, fmaf(bc.x, tx, fmaf(n.x, tz, C.x))),
        fmaf(m3.y, ty, fmaf(bc.y, tx, fmaf(n.y, tz, C.y))),
        fmaf(m3.z, ty, fmaf(bc.z, tx, fmaf(n.z, tz, C.z))));
}

struct KParams {
    const int* seq; const int* kmer; const float* pssm;
    const float* se; const float* emb;
    const float* W0; const float* b0; const float* We; const float* be;
    const float* W1; const float* b1;
    float* kmerT; float* seqT; float* srf_t; float* fragbuf;
    float4* frames; float* FPbuf; float* out;
    unsigned short *WeTH, *WeTL, *W0pTH, *W0pTL, *W1TH, *W1TL;
};

// ======== tables: kmerT via split-bf16 MFMA (vector loads), seqT, weight tables
__global__ __launch_bounds__(256) void tables_kernel(KParams P) {
    const int tid = threadIdx.x;
    const int vb  = blockIdx.x;
    if (vb < 167) {
        const int lane = tid & 63;
        const int wv   = __builtin_amdgcn_readfirstlane(tid >> 6);
        const int q    = lane >> 4;
        const int c16  = lane & 15;
        const int r0   = vb * 64;
        const int n    = wv * 16 + c16;

        bf16x8 BH[8], BL[8];
        #pragma unroll
        for (int kt8 = 0; kt8 < 8; ++kt8)
            #pragma unroll
            for (int j = 0; j < 8; ++j) {
                float w = P.W0[(16 + kt8 * 32 + q * 8 + j) * 64 + n];
                unsigned short h, l; split2t(w, h, l);
                BH[kt8][j] = (short)h; BL[kt8][j] = (short)l;
            }
        f32x4 acc[4];
        #pragma unroll
        for (int t = 0; t < 4; ++t) acc[t] = (f32x4){0.f, 0.f, 0.f, 0.f};
        #pragma unroll
        for (int kt8 = 0; kt8 < 8; ++kt8) {
            #pragma unroll
            for (int t = 0; t < 4; ++t) {
                int rr = r0 + t * 16 + c16;
                if (rr > 10647) rr = 10647;
                const float* ap = P.emb + rr * 256 + kt8 * 32 + q * 8;
                float4 a0 = *(const float4*)ap;
                float4 a1 = *(const float4*)(ap + 4);
                bf16x8 ah, al;
                unsigned short h, l;
                split2t(a0.x, h, l); ah[0] = (short)h; al[0] = (short)l;
                split2t(a0.y, h, l); ah[1] = (short)h; al[1] = (short)l;
                split2t(a0.z, h, l); ah[2] = (short)h; al[2] = (short)l;
                split2t(a0.w, h, l); ah[3] = (short)h; al[3] = (short)l;
                split2t(a1.x, h, l); ah[4] = (short)h; al[4] = (short)l;
                split2t(a1.y, h, l); ah[5] = (short)h; al[5] = (short)l;
                split2t(a1.z, h, l); ah[6] = (short)h; al[6] = (short)l;
                split2t(a1.w, h, l); ah[7] = (short)h; al[7] = (short)l;
                acc[t] = __builtin_amdgcn_mfma_f32_16x16x32_bf16(ah, BH[kt8], acc[t], 0, 0, 0);
                acc[t] = __builtin_amdgcn_mfma_f32_16x16x32_bf16(al, BH[kt8], acc[t], 0, 0, 0);
                acc[t] = __builtin_amdgcn_mfma_f32_16x16x32_bf16(ah, BL[kt8], acc[t], 0, 0, 0);
            }
        }
        #pragma unroll
        for (int t = 0; t < 4; ++t)
            #pragma unroll
            for (int r = 0; r < 4; ++r) {
                int row = r0 + t * 16 + q * 4 + r;
                if (row < 10648) P.kmerT[row * 64 + n] = acc[t][r];
            }
    } else if (vb < 172) {
        // seqT[r][j] = seq_embed[r]@W0[0:16] + b0[j] + 0.5*sum_c W0p[c][j]
        int e = (vb - 167) * 256 + tid;
        int r = e >> 6, j = e & 63;
        float acc = P.b0[j];
        #pragma unroll
        for (int k = 0; k < 16; ++k)
            acc = fmaf(P.se[r * 16 + k], P.W0[k * 64 + j], acc);
        float cs = 0.f;
        #pragma unroll
        for (int c = 0; c < 21; ++c) cs += P.W0[(272 + c) * 64 + j];
        P.seqT[r * 64 + j] = acc + 0.5f * cs;
    } else {
        #pragma unroll
        for (int i = 0; i < 16; ++i) {
            int e = i * 256 + tid;
            int k = e >> 6, n = e & 63;
            unsigned short h, l; split2(P.We[k * 64 + n], h, l);
            P.WeTH[n * 64 + k] = h; P.WeTL[n * 64 + k] = l;
        }
        #pragma unroll
        for (int i = 0; i < 8; ++i) {
            int e = i * 256 + tid;
            int k = e >> 6, n = e & 63;
            float w = (k < 21) ? P.W0[(272 + k) * 64 + n] : 0.f;
            unsigned short h, l; split2(w, h, l);
            P.W0pTH[n * 32 + k] = h; P.W0pTL[n * 32 + k] = l;
        }
        #pragma unroll
        for (int i = 0; i < 4; ++i) {
            int e = i * 256 + tid;
            int k = e >> 4, c = e & 15;
            float w = (c < 9) ? P.W1[k * 9 + c] : 0.f;
            unsigned short h, l; split2(w, h, l);
            P.W1TH[c * 64 + k] = h; P.W1TL[c * 64 + k] = l;
        }
    }
}

// ======== split-bf16 MFMA MLP — r15: wave-owns-tile, ZERO barriers ===========
// r14 post-mortem: removing 2.3M bank-conflict cycles changed dur by ~1us ->
// conflicts were off the critical path; the kernel is barrier-phase-drain
// bound (5 lockstep phases, ~2.8 blocks/CU of cover, all pipes <40%).
// r15: flip wave decomposition N-split -> M-split. Each wave owns 16 ROWS and
// computes all 64 cols, so the inter-layer LDS round-trip is wave-PRIVATE:
// write D / read next-layer A in the wave's own 16x64 strip, ordered by the
// in-order per-wave LDS pipeline + data deps (write value <- MFMA <- read).
// No __syncthreads anywhere. Per-element FLOP order unchanged -> bit-identical
// output. Cost: each wave loads full We/W0p/W1 tables (24KB total, L1-hot).
// LDS 16KiB/block (pssm staged overlaid on H; single H buffer is safe since
// the A-reads complete before D-writes by data dependence).
__global__ __launch_bounds__(256) void mlp_kernel(KParams P) {
    __shared__ __align__(16) unsigned char SMEM[16384];

    const int tid  = threadIdx.x;
    const int lane = tid & 63;
    const int wv   = __builtin_amdgcn_readfirstlane(tid >> 6);
    const int q    = lane >> 4;
    const int c16  = lane & 15;
    const int m0   = blockIdx.x * 64;

    // wave-private regions: H strip [16][64] shorts (swizzled), h and l planes;
    // pssm staging [16][32] overlaid on the H planes (safe: read into regs
    // before first H write, enforced by data dependence through the MFMAs).
    unsigned short* Hh  = (unsigned short*)SMEM + wv * 1024;
    unsigned short* Hl  = (unsigned short*)(SMEM + 8192) + wv * 1024;
    unsigned short* Pph = Hh;
    unsigned short* Ppl = Hl;

    // ---- indices: one coalesced load per lane (block's 64 rows), then
    //      redistribute within the wave; only 4 distinct rows per lane now ----
    const int myseq = P.seq[m0 + lane];
    const int mykm  = P.kmer[m0 + lane];
    int sidx[4], kidx[4];
    #pragma unroll
    for (int r = 0; r < 4; ++r) {
        int src = (wv * 16 + q * 4 + r) << 2;
        sidx[r] = __builtin_amdgcn_ds_bpermute(src, myseq);
        kidx[r] = __builtin_amdgcn_ds_bpermute(src, mykm);
    }
    float g[4][4];
    #pragma unroll
    for (int nt = 0; nt < 4; ++nt)
        #pragma unroll
        for (int r = 0; r < 4; ++r)
            g[nt][r] = P.seqT[sidx[r] * 64 + nt * 16 + c16]
                     + P.kmerT[kidx[r] * 64 + nt * 16 + c16];

    // ---- stage this wave's 16 pssm rows (centered, trunc-split) ----
    const float* prow = P.pssm + (m0 + wv * 16) * 21;
    for (int i = lane; i < 16 * 21; i += 64) {
        float v = prow[i] - 0.5f;
        unsigned short h, l; split2t(v, h, l);
        int row = i / 21, col = i - row * 21;
        Pph[row * 32 + col] = h;
        Ppl[row * 32 + col] = l;
    }
    for (int i = lane; i < 16 * 11; i += 64) {
        int row = i / 11, col = 21 + (i - row * 11);
        Pph[row * 32 + col] = 0;
        Ppl[row * 32 + col] = 0;
    }

    // ---- biases ----
    float be4[4];
    #pragma unroll
    for (int nt = 0; nt < 4; ++nt) be4[nt] = P.be[nt * 16 + c16];
    const float b1h = (c16 < 9) ? P.b1[c16] : 0.f;

    // ---- layer 0: A = wave's pssm strip, B = W0p (4 col-tiles) ----
    bf16x8 pah = *(const bf16x8*)&Pph[c16 * 32 + q * 8];
    bf16x8 pal = *(const bf16x8*)&Ppl[c16 * 32 + q * 8];
    f32x4 acc[4];
    #pragma unroll
    for (int nt = 0; nt < 4; ++nt) {
        const int wo = (nt * 16 + c16) * 32 + q * 8;
        bf16x8 w0h = *(const bf16x8*)(P.W0pTH + wo);
        bf16x8 w0l = *(const bf16x8*)(P.W0pTL + wo);
        f32x4 a = (f32x4){0.f, 0.f, 0.f, 0.f};
        a = __builtin_amdgcn_mfma_f32_16x16x32_bf16(pah, w0h, a, 0, 0, 0);
        a = __builtin_amdgcn_mfma_f32_16x16x32_bf16(pal, w0h, a, 0, 0, 0);
        a = __builtin_amdgcn_mfma_f32_16x16x32_bf16(pah, w0l, a, 0, 0, 0);
        acc[nt] = a;
    }
    #pragma unroll
    for (int nt = 0; nt < 4; ++nt)
        #pragma unroll
        for (int r = 0; r < 4; ++r) {
            unsigned short h, l; split2t(acc[nt][r] + g[nt][r], h, l);
            Hh[hsw16(q * 4 + r, nt * 16 + c16)] = h;
            Hl[hsw16(q * 4 + r, nt * 16 + c16)] = l;
        }

    // ---- layers 1,2: H -> H (relu), wave-private, no barriers ----
    #pragma unroll
    for (int layer = 0; layer < 2; ++layer) {
        bf16x8 ahk[2], alk[2];
        #pragma unroll
        for (int kk = 0; kk < 2; ++kk) {
            ahk[kk] = *(const bf16x8*)&Hh[hsw16(c16, kk * 32 + q * 8)];
            alk[kk] = *(const bf16x8*)&Hl[hsw16(c16, kk * 32 + q * 8)];
        }
        f32x4 a1[4];
        #pragma unroll
        for (int nt = 0; nt < 4; ++nt) {
            f32x4 a = (f32x4){be4[nt], be4[nt], be4[nt], be4[nt]};
            #pragma unroll
            for (int kk = 0; kk < 2; ++kk) {
                const int wo = (nt * 16 + c16) * 64 + kk * 32 + q * 8;
                bf16x8 weh = *(const bf16x8*)(P.WeTH + wo);
                bf16x8 wel = *(const bf16x8*)(P.WeTL + wo);
                a = __builtin_amdgcn_mfma_f32_16x16x32_bf16(ahk[kk], weh, a, 0, 0, 0);
                a = __builtin_amdgcn_mfma_f32_16x16x32_bf16(alk[kk], weh, a, 0, 0, 0);
                a = __builtin_amdgcn_mfma_f32_16x16x32_bf16(ahk[kk], wel, a, 0, 0, 0);
            }
            a1[nt] = a;
        }
        #pragma unroll
        for (int nt = 0; nt < 4; ++nt)
            #pragma unroll
            for (int r = 0; r < 4; ++r) {
                unsigned short h, l; split2t(fmaxf(a1[nt][r], 0.f), h, l);
                Hh[hsw16(q * 4 + r, nt * 16 + c16)] = h;
                Hl[hsw16(q * 4 + r, nt * 16 + c16)] = l;
            }
    }

    // ---- head: 16x9 output from wave's own strip ----
    {
        f32x4 hacc = (f32x4){b1h, b1h, b1h, b1h};
        #pragma unroll
        for (int kk = 0; kk < 2; ++kk) {
            bf16x8 ah = *(const bf16x8*)&Hh[hsw16(c16, kk * 32 + q * 8)];
            bf16x8 al = *(const bf16x8*)&Hl[hsw16(c16, kk * 32 + q * 8)];
            const int wo = c16 * 64 + kk * 32 + q * 8;
            bf16x8 w1h = *(const bf16x8*)(P.W1TH + wo);
            bf16x8 w1l = *(const bf16x8*)(P.W1TL + wo);
            hacc = __builtin_amdgcn_mfma_f32_16x16x32_bf16(ah, w1h, hacc, 0, 0, 0);
            hacc = __builtin_amdgcn_mfma_f32_16x16x32_bf16(al, w1h, hacc, 0, 0, 0);
            hacc = __builtin_amdgcn_mfma_f32_16x16x32_bf16(ah, w1l, hacc, 0, 0, 0);
        }
        if (c16 < 9) {
            #pragma unroll
            for (int r = 0; r < 4; ++r) {
                int pos = m0 + wv * 16 + q * 4 + r;
                int l = pos >> 8, b = pos & 255;
                P.srf_t[(l * 9 + c16) * 256 + b] = hacc[r];
            }
        }
    }
}

// ======== extend: depth-3 prefetch; emits per-fragment frame + endpoint ========
__global__ __launch_bounds__(64) void extend_kernel(KParams P) {
    int frag = blockIdx.x >> 2;
    int bb   = ((blockIdx.x & 3) << 6) + threadIdx.x;

    float3 A  = make_float3(-0.70710678118654752f, 1.22474487139158905f, 0.f);
    float3 Bv = make_float3(-1.41421356237309505f, 0.f, 0.f);
    float3 C  = make_float3(0.f, 0.f, 0.f);

    float ct0[9], ct1[9], ct2[9], ct3[9];
    #pragma unroll
    for (int m = 0; m < 9; ++m) {
        ct0[m] = P.srf_t[((frag * 32 + 0) * 9 + m) * 256 + bb];
        ct1[m] = P.srf_t[((frag * 32 + 1) * 9 + m) * 256 + bb];
        ct2[m] = P.srf_t[((frag * 32 + 2) * 9 + m) * 256 + bb];
    }
    for (int ll = 0; ll < 32; ++ll) {
        if (ll < 29) {
            #pragma unroll
            for (int m = 0; m < 9; ++m)
                ct3[m] = P.srf_t[((frag * 32 + ll + 3) * 9 + m) * 256 + bb];
        } else {
            #pragma unroll
            for (int m = 0; m < 9; ++m) ct3[m] = 0.f;
        }
        #pragma unroll
        for (int s3 = 0; s3 < 3; ++s3) {
            float3 bc, nn, m3;
            nerf_frame(A, Bv, C, bc, nn, m3);
            float3 d = nerf_place(C, bc, m3, nn,
                                  ct0[3 * s3 + 0], ct0[3 * s3 + 1], ct0[3 * s3 + 2]);
            int row = frag * 96 + ll * 3 + s3;
            P.fragbuf[(row * 3 + 0) * 256 + bb] = d.x;
            P.fragbuf[(row * 3 + 1) * 256 + bb] = d.y;
            P.fragbuf[(row * 3 + 2) * 256 + bb] = d.z;
            A = Bv; Bv = C; C = d;
        }
        #pragma unroll
        for (int m = 0; m < 9; ++m) { ct0[m] = ct1[m]; ct1[m] = ct2[m]; ct2[m] = ct3[m]; }
    }
    float3 bc, nn, m3;
    nerf_frame(A, Bv, C, bc, nn, m3);
    P.FPbuf[(frag * 12 + 0)  * 256 + bb] = bc.x;
    P.FPbuf[(frag * 12 + 1)  * 256 + bb] = bc.y;
    P.FPbuf[(frag * 12 + 2)  * 256 + bb] = bc.z;
    P.FPbuf[(frag * 12 + 3)  * 256 + bb] = m3.x;
    P.FPbuf[(frag * 12 + 4)  * 256 + bb] = m3.y;
    P.FPbuf[(frag * 12 + 5)  * 256 + bb] = m3.z;
    P.FPbuf[(frag * 12 + 6)  * 256 + bb] = nn.x;
    P.FPbuf[(frag * 12 + 7)  * 256 + bb] = nn.y;
    P.FPbuf[(frag * 12 + 8)  * 256 + bb] = nn.z;
    P.FPbuf[(frag * 12 + 9)  * 256 + bb] = C.x;
    P.FPbuf[(frag * 12 + 10) * 256 + bb] = C.y;
    P.FPbuf[(frag * 12 + 11) * 256 + bb] = C.z;
}

// ======== carry: rotation-composition over fragment constants (LDS-staged) ====
__global__ __launch_bounds__(256) void carry_kernel(KParams P) {
    __shared__ float S[384][16];
    const int tid  = threadIdx.x;
    const int base = blockIdx.x * 16;
    for (int i = tid; i < 384 * 16; i += 256) {
        int row = i >> 4, col = i & 15;
        S[row][col] = P.FPbuf[row * 256 + base + col];
    }
    __syncthreads();
    if (tid < 16) {
        int bb = base + tid;
        float3 ob = make_float3(1.f, 0.f, 0.f);
        float3 om = make_float3(0.f, 1.f, 0.f);
        float3 on = make_float3(0.f, 0.f, 1.f);
        float3 c  = make_float3(0.f, 0.f, 0.f);
        for (int f = 0; f < 32; ++f) {
            int fb = (f * 256 + bb) * 3;
            P.frames[fb + 0] = make_float4(ob.x, ob.y, ob.z, om.x);
            P.frames[fb + 1] = make_float4(om.y, om.z, on.x, on.y);
            P.frames[fb + 2] = make_float4(on.z, c.x, c.y, c.z);

            int r0 = f * 12;
            float3 Fb = make_float3(S[r0+0][tid], S[r0+1][tid], S[r0+2][tid]);
            float3 Fm = make_float3(S[r0+3][tid], S[r0+4][tid], S[r0+5][tid]);
            float3 Fn = make_float3(S[r0+6][tid], S[r0+7][tid], S[r0+8][tid]);
            float3 p  = make_float3(S[r0+9][tid], S[r0+10][tid], S[r0+11][tid]);

            float3 nb = make_float3(
                fmaf(ob.x,Fb.x, fmaf(om.x,Fb.y, on.x*Fb.z)),
                fmaf(ob.y,Fb.x, fmaf(om.y,Fb.y, on.y*Fb.z)),
                fmaf(ob.z,Fb.x, fmaf(om.z,Fb.y, on.z*Fb.z)));
            float3 nm = make_float3(
                fmaf(ob.x,Fm.x, fmaf(om.x,Fm.y, on.x*Fm.z)),
                fmaf(ob.y,Fm.x, fmaf(om.y,Fm.y, on.y*Fm.z)),
                fmaf(ob.z,Fm.x, fmaf(om.z,Fm.y, on.z*Fm.z)));
            float3 nn2 = make_float3(
                fmaf(ob.x,Fn.x, fmaf(om.x,Fn.y, on.x*Fn.z)),
                fmaf(ob.y,Fn.x, fmaf(om.y,Fn.y, on.y*Fn.z)),
                fmaf(ob.z,Fn.x, fmaf(om.z,Fn.y, on.z*Fn.z)));
            float3 nc = make_float3(
                fmaf(ob.x,p.x, fmaf(om.x,p.y, fmaf(on.x,p.z, c.x))),
                fmaf(ob.y,p.x, fmaf(om.y,p.y, fmaf(on.y,p.z, c.y))),
                fmaf(ob.z,p.x, fmaf(om.z,p.y, fmaf(on.z,p.z, c.z))));
            ob = nb; om = nm; on = nn2; c = nc;
        }
    }
}

// ======== apply: 4 rows/block; LDS-staged coalesced output ========
__global__ __launch_bounds__(256) void apply_kernel(KParams P) {
    __shared__ float sm[768];
    const int bb = threadIdx.x;
    #pragma unroll 1
    for (int i = 0; i < 4; ++i) {
        const int row  = blockIdx.x * 4 + i;
        const int frag = row / 96;

        float fx = P.fragbuf[(row * 3 + 0) * 256 + bb];
        float fy = P.fragbuf[(row * 3 + 1) * 256 + bb];
        float fz = P.fragbuf[(row * 3 + 2) * 256 + bb];

        int fb = (frag * 256 + bb) * 3;
        float4 f0 = P.frames[fb + 0];
        float4 f1 = P.frames[fb + 1];
        float4 f2 = P.frames[fb + 2];

        float ox = f2.y + f0.x * fx + f0.w * fy + f1.z * fz;
        float oy = f2.z + f0.y * fx + f1.x * fy + f1.w * fz;
        float oz = f2.w + f0.z * fx + f1.y * fy + f2.x * fz;

        __syncthreads();   // prior iteration's sm reads complete
        sm[bb * 3 + 0] = ox;
        sm[bb * 3 + 1] = oy;
        sm[bb * 3 + 2] = oz;
        __syncthreads();

        int base = row * 768;
        P.out[base + bb]       = sm[bb];
        P.out[base + 256 + bb] = sm[256 + bb];
        P.out[base + 512 + bb] = sm[512 + bb];
    }
}

// ======== host launch: 5-dispatch path (coop fusion measured 2.3x worse:
// grid.sync ~90us each on 8-XCD MI355X — r10) ========
extern "C" void kernel_launch(void* const* d_in, const int* in_sizes, int n_in,
                              void* d_out, int out_size, void* d_ws, size_t ws_size,
                              hipStream_t stream) {
    float* ws      = (float*)d_ws;
    float* kmerT   = ws;                       // 10648*64 = 681472
    float* seqT    = kmerT + 681472;           // 1280
    float* srf_t   = seqT + 1280;              // 2359296
    float* fragbuf = srf_t + 2359296;          // 2359296
    float* frames  = fragbuf + 2359296;        // 98304 (float4-accessed)
    float* FPbuf   = frames + 98304;           // 98304

    // split weight tables alias fragbuf (tables writes -> mlp reads -> extend
    // overwrites; strictly ordered by kernel boundaries)
    unsigned short* WeTH  = (unsigned short*)fragbuf;
    unsigned short* WeTL  = WeTH + 4096;
    unsigned short* W0pTH = WeTL + 4096;
    unsigned short* W0pTL = W0pTH + 2048;
    unsigned short* W1TH  = W0pTL + 2048;
    unsigned short* W1TL  = W1TH + 1024;

    KParams P;
    P.seq  = (const int*)d_in[0];
    P.kmer = (const int*)d_in[1];
    P.pssm = (const float*)d_in[2];
    P.se   = (const float*)d_in[4];
    P.emb  = (const float*)d_in[5];
    P.W0   = (const float*)d_in[6];
    P.b0   = (const float*)d_in[7];
    P.We   = (const float*)d_in[8];
    P.be   = (const float*)d_in[9];
    P.W1   = (const float*)d_in[10];
    P.b1   = (const float*)d_in[11];
    P.kmerT = kmerT; P.seqT = seqT; P.srf_t = srf_t; P.fragbuf = fragbuf;
    P.frames = (float4*)frames; P.FPbuf = FPbuf; P.out = (float*)d_out;
    P.WeTH = WeTH; P.WeTL = WeTL; P.W0pTH = W0pTH; P.W0pTL = W0pTL;
    P.W1TH = W1TH; P.W1TL = W1TL;

    hipLaunchKernelGGL(tables_kernel, dim3(173),  dim3(256), 0, stream, P);
    hipLaunchKernelGGL(mlp_kernel,    dim3(4096), dim3(256), 0, stream, P);
    hipLaunchKernelGGL(extend_kernel, dim3(128),  dim3(64),  0, stream, P);
    hipLaunchKernelGGL(carry_kernel,  dim3(16),   dim3(256), 0, stream, P);
    hipLaunchKernelGGL(apply_kernel,  dim3(768),  dim3(256), 0, stream, P);
}

// Round 4
// 197.704 us; speedup vs baseline: 1.1532x; 1.1532x over previous
//
#include <hip/hip_runtime.h>
#include <math.h>

typedef short bf16x8 __attribute__((ext_vector_type(8)));
typedef float f32x4  __attribute__((ext_vector_type(4)));

// round-to-nearest-even float -> bf16 bits
__device__ __forceinline__ unsigned short f2bf(float x) {
    unsigned int u = __float_as_uint(x);
    return (unsigned short)((u + 0x7FFFu + ((u >> 16) & 1u)) >> 16);
}
__device__ __forceinline__ float bf2f(unsigned short h) {
    return __uint_as_float(((unsigned int)h) << 16);
}
// RNE split (precompute path)
__device__ __forceinline__ void split2(float x, unsigned short& h, unsigned short& l) {
    h = f2bf(x);
    l = f2bf(x - bf2f(h));
}
// truncation split (hot path): hi = trunc(x), lo = RNE(x-hi); combined rel err ~2^-17
__device__ __forceinline__ void split2t(float x, unsigned short& h, unsigned short& l) {
    unsigned int u = __float_as_uint(x);
    h = (unsigned short)(u >> 16);
    float r = x - __uint_as_float(u & 0xFFFF0000u);
    l = f2bf(r);
}

// XOR-swizzled H index (shorts): stride 64 shorts (128 B rows).
// Bank analysis (32 banks x 4B): row stride = 32 dwords == 0 mod 32, so bank is
// set by the 16B chunk only; chunk' = chunk ^ (row&7) spreads 16 consecutive
// rows over 8 chunks = 32 banks -> 2-way on b128 reads (free, m136).
// Measured 688K conflicts vs 3.05M for the old stride-72 pad (r13/r14) — keep.
__device__ __forceinline__ int hsw(int row, int col) {
    return (row << 6) + ((((col >> 3) ^ (row & 7)) << 3) | (col & 7));
}

__device__ __forceinline__ float inv_norm3(float x, float y, float z) {
    float d = fmaf(x, x, fmaf(y, y, z * z));
    return rsqrtf(fmaxf(d, 1e-24f));
}
__device__ __forceinline__ float3 f3sub(float3 a, float3 b) {
    return make_float3(a.x - b.x, a.y - b.y, a.z - b.z);
}
__device__ __forceinline__ float3 f3cross(float3 a, float3 b) {
    return make_float3(a.y * b.z - a.z * b.y,
                       a.z * b.x - a.x * b.z,
                       a.x * b.y - a.y * b.x);
}
// NeRF frame, parallel normalizations (n from unnormalized w: same direction)
__device__ __forceinline__ void nerf_frame(const float3& A, const float3& Bv,
                                           const float3& C, float3& bc,
                                           float3& n, float3& m3) {
    float3 w  = f3sub(C, Bv);
    float3 v  = f3sub(Bv, A);
    float3 cr = f3cross(v, w);
    float iw = inv_norm3(w.x, w.y, w.z);
    float ic = inv_norm3(cr.x, cr.y, cr.z);
    bc = make_float3(w.x * iw, w.y * iw, w.z * iw);
    n  = make_float3(cr.x * ic, cr.y * ic, cr.z * ic);
    m3 = f3cross(n, bc);
}
__device__ __forceinline__ float3 nerf_place(const float3& C, const float3& bc,
                                             const float3& m3, const float3& n,
                                             float tx, float ty, float tz) {
    return make_float3(
        fmaf(m3.x, ty, fmaf(bc.x, tx, fmaf(n.x, tz, C.x))),
        fmaf(m3.y, ty, fmaf(bc.y, tx, fmaf(n.y, tz, C.y))),
        fmaf(m3.z, ty, fmaf(bc.z, tx, fmaf(n.z, tz, C.z))));
}

struct KParams {
    const int* seq; const int* kmer; const float* pssm;
    const float* se; const float* emb;
    const float* W0; const float* b0; const float* We; const float* be;
    const float* W1; const float* b1;
    float* kmerT; float* seqT; float* srf_t; float* fragbuf;
    float4* frames; float* FPbuf; float* out;
    unsigned short *WeTH, *WeTL, *W0pTH, *W0pTL, *W1TH, *W1TL;
};

// ======== tables: kmerT via split-bf16 MFMA (vector loads), seqT, weight tables
__global__ __launch_bounds__(256) void tables_kernel(KParams P) {
    const int tid = threadIdx.x;
    const int vb  = blockIdx.x;
    if (vb < 167) {
        const int lane = tid & 63;
        const int wv   = __builtin_amdgcn_readfirstlane(tid >> 6);
        const int q    = lane >> 4;
        const int c16  = lane & 15;
        const int r0   = vb * 64;
        const int n    = wv * 16 + c16;

        bf16x8 BH[8], BL[8];
        #pragma unroll
        for (int kt8 = 0; kt8 < 8; ++kt8)
            #pragma unroll
            for (int j = 0; j < 8; ++j) {
                float w = P.W0[(16 + kt8 * 32 + q * 8 + j) * 64 + n];
                unsigned short h, l; split2t(w, h, l);
                BH[kt8][j] = (short)h; BL[kt8][j] = (short)l;
            }
        f32x4 acc[4];
        #pragma unroll
        for (int t = 0; t < 4; ++t) acc[t] = (f32x4){0.f, 0.f, 0.f, 0.f};
        #pragma unroll
        for (int kt8 = 0; kt8 < 8; ++kt8) {
            #pragma unroll
            for (int t = 0; t < 4; ++t) {
                int rr = r0 + t * 16 + c16;
                if (rr > 10647) rr = 10647;
                const float* ap = P.emb + rr * 256 + kt8 * 32 + q * 8;
                float4 a0 = *(const float4*)ap;
                float4 a1 = *(const float4*)(ap + 4);
                bf16x8 ah, al;
                unsigned short h, l;
                split2t(a0.x, h, l); ah[0] = (short)h; al[0] = (short)l;
                split2t(a0.y, h, l); ah[1] = (short)h; al[1] = (short)l;
                split2t(a0.z, h, l); ah[2] = (short)h; al[2] = (short)l;
                split2t(a0.w, h, l); ah[3] = (short)h; al[3] = (short)l;
                split2t(a1.x, h, l); ah[4] = (short)h; al[4] = (short)l;
                split2t(a1.y, h, l); ah[5] = (short)h; al[5] = (short)l;
                split2t(a1.z, h, l); ah[6] = (short)h; al[6] = (short)l;
                split2t(a1.w, h, l); ah[7] = (short)h; al[7] = (short)l;
                acc[t] = __builtin_amdgcn_mfma_f32_16x16x32_bf16(ah, BH[kt8], acc[t], 0, 0, 0);
                acc[t] = __builtin_amdgcn_mfma_f32_16x16x32_bf16(al, BH[kt8], acc[t], 0, 0, 0);
                acc[t] = __builtin_amdgcn_mfma_f32_16x16x32_bf16(ah, BL[kt8], acc[t], 0, 0, 0);
            }
        }
        #pragma unroll
        for (int t = 0; t < 4; ++t)
            #pragma unroll
            for (int r = 0; r < 4; ++r) {
                int row = r0 + t * 16 + q * 4 + r;
                if (row < 10648) P.kmerT[row * 64 + n] = acc[t][r];
            }
    } else if (vb < 172) {
        // seqT[r][j] = seq_embed[r]@W0[0:16] + b0[j] + 0.5*sum_c W0p[c][j]
        int e = (vb - 167) * 256 + tid;
        int r = e >> 6, j = e & 63;
        float acc = P.b0[j];
        #pragma unroll
        for (int k = 0; k < 16; ++k)
            acc = fmaf(P.se[r * 16 + k], P.W0[k * 64 + j], acc);
        float cs = 0.f;
        #pragma unroll
        for (int c = 0; c < 21; ++c) cs += P.W0[(272 + c) * 64 + j];
        P.seqT[r * 64 + j] = acc + 0.5f * cs;
    } else {
        #pragma unroll
        for (int i = 0; i < 16; ++i) {
            int e = i * 256 + tid;
            int k = e >> 6, n = e & 63;
            unsigned short h, l; split2(P.We[k * 64 + n], h, l);
            P.WeTH[n * 64 + k] = h; P.WeTL[n * 64 + k] = l;
        }
        #pragma unroll
        for (int i = 0; i < 8; ++i) {
            int e = i * 256 + tid;
            int k = e >> 6, n = e & 63;
            float w = (k < 21) ? P.W0[(272 + k) * 64 + n] : 0.f;
            unsigned short h, l; split2(w, h, l);
            P.W0pTH[n * 32 + k] = h; P.W0pTL[n * 32 + k] = l;
        }
        #pragma unroll
        for (int i = 0; i < 4; ++i) {
            int e = i * 256 + tid;
            int k = e >> 4, c = e & 15;
            float w = (c < 9) ? P.W1[k * 9 + c] : 0.f;
            unsigned short h, l; split2(w, h, l);
            P.W1TH[c * 64 + k] = h; P.W1TL[c * 64 + k] = l;
        }
    }
}

// ======== split-bf16 MFMA MLP — r16 =========================================
// r15 post-mortem: M-split (wave-owns-tile) cratered (102us, VGPR 44) — the
// allocator wouldn't hold the 4x weight set, so every MFMA waited on a fresh
// global weight load. Revert to the r14 N-split skeleton (weights = 10 frags
// = 40 VGPR, proven 47.5us), and instead delete the pssm LDS staging phase:
// the L0 A-fragment (row t*16+c16, cols q*8..q*8+7) is 8 CONSECUTIVE pssm
// floats -> load per-lane directly from global (col<21 exec-masked; pad cols
// are exact 0), split2t in-register. Removes the stage loop + zero-fill +
// /21 divisions + 8 ds_read_b128 + ONE barrier (3 left), and front-loads all
// global latency (gathers + pssm issue together at block start). Same split
// values feed the same MFMA sequence -> bit-identical output.
__global__ __launch_bounds__(256, 4) void mlp_kernel(KParams P) {
    __shared__ __align__(16) unsigned char SMEM[32768];
    unsigned short* Hah = (unsigned short*)(SMEM);            // swizzled, 8192 B
    unsigned short* Hal = (unsigned short*)(SMEM + 8192);
    unsigned short* Hbh = (unsigned short*)(SMEM + 16384);
    unsigned short* Hbl = (unsigned short*)(SMEM + 24576);

    const int tid  = threadIdx.x;
    const int lane = tid & 63;
    const int wv   = __builtin_amdgcn_readfirstlane(tid >> 6);
    const int q    = lane >> 4;
    const int c16  = lane & 15;
    const int m0   = blockIdx.x * 64;
    const int n    = wv * 16 + c16;

    // ---- indices: one coalesced load per lane, redistribute via bpermute;
    //      gathers issue immediately (longest chain: load->bpermute->L2 gather)
    const int myseq = P.seq[m0 + lane];
    const int mykm  = P.kmer[m0 + lane];
    float g[4][4];
    #pragma unroll
    for (int t = 0; t < 4; ++t)
        #pragma unroll
        for (int r = 0; r < 4; ++r) {
            int src = (t * 16 + q * 4 + r) << 2;
            int s  = __builtin_amdgcn_ds_bpermute(src, myseq);
            int km = __builtin_amdgcn_ds_bpermute(src, mykm);
            g[t][r] = P.seqT[s * 64 + n] + P.kmerT[km * 64 + n];
        }

    // ---- per-lane direct pssm A-fragments (no LDS staging, no stage barrier)
    //      lane (c16,q) owns rows t*16+c16, cols q*8..q*8+7; cols>=21 are the
    //      zero pad (exec-masked loads keep OOB lanes off the bus).
    bf16x8 pah[4], pal[4];
    #pragma unroll
    for (int t = 0; t < 4; ++t) {
        const float* prow = P.pssm + (m0 + t * 16 + c16) * 21;
        #pragma unroll
        for (int j = 0; j < 8; ++j) {
            const int col = q * 8 + j;
            float v = 0.f;
            if (col < 21) v = prow[col] - 0.5f;
            unsigned short h, l; split2t(v, h, l);
            pah[t][j] = (short)h; pal[t][j] = (short)l;
        }
    }

    // ---- weight fragments + biases (L1/L2-hot 16B loads) ----
    bf16x8 WeH[2], WeL[2], W1H[2], W1L[2], W0H, W0L;
    #pragma unroll
    for (int kk = 0; kk < 2; ++kk) {
        WeH[kk] = *(const bf16x8*)(P.WeTH + n * 64 + kk * 32 + q * 8);
        WeL[kk] = *(const bf16x8*)(P.WeTL + n * 64 + kk * 32 + q * 8);
        W1H[kk] = *(const bf16x8*)(P.W1TH + c16 * 64 + kk * 32 + q * 8);
        W1L[kk] = *(const bf16x8*)(P.W1TL + c16 * 64 + kk * 32 + q * 8);
    }
    W0H = *(const bf16x8*)(P.W0pTH + n * 32 + q * 8);
    W0L = *(const bf16x8*)(P.W0pTL + n * 32 + q * 8);
    const float be_n = P.be[n];
    const float b1h  = (c16 < 9) ? P.b1[c16] : 0.f;

    // ---- layer 0: A from registers; zero-init MFMA, add gathers late ----
    f32x4 acc[4];
    #pragma unroll
    for (int t = 0; t < 4; ++t) acc[t] = (f32x4){0.f, 0.f, 0.f, 0.f};
    #pragma unroll
    for (int t = 0; t < 4; ++t) {
        acc[t] = __builtin_amdgcn_mfma_f32_16x16x32_bf16(pah[t], W0H, acc[t], 0, 0, 0);
        acc[t] = __builtin_amdgcn_mfma_f32_16x16x32_bf16(pal[t], W0H, acc[t], 0, 0, 0);
        acc[t] = __builtin_amdgcn_mfma_f32_16x16x32_bf16(pah[t], W0L, acc[t], 0, 0, 0);
    }
    #pragma unroll
    for (int t = 0; t < 4; ++t)
        #pragma unroll
        for (int r = 0; r < 4; ++r) {
            unsigned short h, l; split2t(acc[t][r] + g[t][r], h, l);
            Hah[hsw(t * 16 + q * 4 + r, n)] = h;
            Hal[hsw(t * 16 + q * 4 + r, n)] = l;
        }
    __syncthreads();   // h0 ready

    // ---- layer 1: Ha -> Hb (relu) ----
    {
        f32x4 a1[4];
        #pragma unroll
        for (int t = 0; t < 4; ++t) {
            a1[t] = (f32x4){be_n, be_n, be_n, be_n};
            #pragma unroll
            for (int kk = 0; kk < 2; ++kk) {
                bf16x8 ah = *(const bf16x8*)&Hah[hsw(t * 16 + c16, kk * 32 + q * 8)];
                bf16x8 al = *(const bf16x8*)&Hal[hsw(t * 16 + c16, kk * 32 + q * 8)];
                a1[t] = __builtin_amdgcn_mfma_f32_16x16x32_bf16(ah, WeH[kk], a1[t], 0, 0, 0);
                a1[t] = __builtin_amdgcn_mfma_f32_16x16x32_bf16(al, WeH[kk], a1[t], 0, 0, 0);
                a1[t] = __builtin_amdgcn_mfma_f32_16x16x32_bf16(ah, WeL[kk], a1[t], 0, 0, 0);
            }
        }
        #pragma unroll
        for (int t = 0; t < 4; ++t)
            #pragma unroll
            for (int r = 0; r < 4; ++r) {
                unsigned short h, l; split2t(fmaxf(a1[t][r], 0.f), h, l);
                Hbh[hsw(t * 16 + q * 4 + r, n)] = h;
                Hbl[hsw(t * 16 + q * 4 + r, n)] = l;
            }
        __syncthreads();
    }
    // ---- layer 2: Hb -> Ha (relu) ----
    {
        f32x4 a2[4];
        #pragma unroll
        for (int t = 0; t < 4; ++t) {
            a2[t] = (f32x4){be_n, be_n, be_n, be_n};
            #pragma unroll
            for (int kk = 0; kk < 2; ++kk) {
                bf16x8 ah = *(const bf16x8*)&Hbh[hsw(t * 16 + c16, kk * 32 + q * 8)];
                bf16x8 al = *(const bf16x8*)&Hbl[hsw(t * 16 + c16, kk * 32 + q * 8)];
                a2[t] = __builtin_amdgcn_mfma_f32_16x16x32_bf16(ah, WeH[kk], a2[t], 0, 0, 0);
                a2[t] = __builtin_amdgcn_mfma_f32_16x16x32_bf16(al, WeH[kk], a2[t], 0, 0, 0);
                a2[t] = __builtin_amdgcn_mfma_f32_16x16x32_bf16(ah, WeL[kk], a2[t], 0, 0, 0);
            }
        }
        #pragma unroll
        for (int t = 0; t < 4; ++t)
            #pragma unroll
            for (int r = 0; r < 4; ++r) {
                unsigned short h, l; split2t(fmaxf(a2[t][r], 0.f), h, l);
                Hah[hsw(t * 16 + q * 4 + r, n)] = h;
                Hal[hsw(t * 16 + q * 4 + r, n)] = l;
            }
        __syncthreads();
    }
    // ---- head: wave wv does M-tile wv ----
    {
        f32x4 ah4 = (f32x4){b1h, b1h, b1h, b1h};
        #pragma unroll
        for (int kk = 0; kk < 2; ++kk) {
            bf16x8 ah = *(const bf16x8*)&Hah[hsw(wv * 16 + c16, kk * 32 + q * 8)];
            bf16x8 al = *(const bf16x8*)&Hal[hsw(wv * 16 + c16, kk * 32 + q * 8)];
            ah4 = __builtin_amdgcn_mfma_f32_16x16x32_bf16(ah, W1H[kk], ah4, 0, 0, 0);
            ah4 = __builtin_amdgcn_mfma_f32_16x16x32_bf16(al, W1H[kk], ah4, 0, 0, 0);
            ah4 = __builtin_amdgcn_mfma_f32_16x16x32_bf16(ah, W1L[kk], ah4, 0, 0, 0);
        }
        if (c16 < 9) {
            #pragma unroll
            for (int r = 0; r < 4; ++r) {
                int pos = m0 + wv * 16 + q * 4 + r;
                int l = pos >> 8, b = pos & 255;
                P.srf_t[(l * 9 + c16) * 256 + b] = ah4[r];
            }
        }
    }
}

// ======== extend: depth-3 prefetch; emits per-fragment frame + endpoint ========
__global__ __launch_bounds__(64) void extend_kernel(KParams P) {
    int frag = blockIdx.x >> 2;
    int bb   = ((blockIdx.x & 3) << 6) + threadIdx.x;

    float3 A  = make_float3(-0.70710678118654752f, 1.22474487139158905f, 0.f);
    float3 Bv = make_float3(-1.41421356237309505f, 0.f, 0.f);
    float3 C  = make_float3(0.f, 0.f, 0.f);

    float ct0[9], ct1[9], ct2[9], ct3[9];
    #pragma unroll
    for (int m = 0; m < 9; ++m) {
        ct0[m] = P.srf_t[((frag * 32 + 0) * 9 + m) * 256 + bb];
        ct1[m] = P.srf_t[((frag * 32 + 1) * 9 + m) * 256 + bb];
        ct2[m] = P.srf_t[((frag * 32 + 2) * 9 + m) * 256 + bb];
    }
    for (int ll = 0; ll < 32; ++ll) {
        if (ll < 29) {
            #pragma unroll
            for (int m = 0; m < 9; ++m)
                ct3[m] = P.srf_t[((frag * 32 + ll + 3) * 9 + m) * 256 + bb];
        } else {
            #pragma unroll
            for (int m = 0; m < 9; ++m) ct3[m] = 0.f;
        }
        #pragma unroll
        for (int s3 = 0; s3 < 3; ++s3) {
            float3 bc, nn, m3;
            nerf_frame(A, Bv, C, bc, nn, m3);
            float3 d = nerf_place(C, bc, m3, nn,
                                  ct0[3 * s3 + 0], ct0[3 * s3 + 1], ct0[3 * s3 + 2]);
            int row = frag * 96 + ll * 3 + s3;
            P.fragbuf[(row * 3 + 0) * 256 + bb] = d.x;
            P.fragbuf[(row * 3 + 1) * 256 + bb] = d.y;
            P.fragbuf[(row * 3 + 2) * 256 + bb] = d.z;
            A = Bv; Bv = C; C = d;
        }
        #pragma unroll
        for (int m = 0; m < 9; ++m) { ct0[m] = ct1[m]; ct1[m] = ct2[m]; ct2[m] = ct3[m]; }
    }
    float3 bc, nn, m3;
    nerf_frame(A, Bv, C, bc, nn, m3);
    P.FPbuf[(frag * 12 + 0)  * 256 + bb] = bc.x;
    P.FPbuf[(frag * 12 + 1)  * 256 + bb] = bc.y;
    P.FPbuf[(frag * 12 + 2)  * 256 + bb] = bc.z;
    P.FPbuf[(frag * 12 + 3)  * 256 + bb] = m3.x;
    P.FPbuf[(frag * 12 + 4)  * 256 + bb] = m3.y;
    P.FPbuf[(frag * 12 + 5)  * 256 + bb] = m3.z;
    P.FPbuf[(frag * 12 + 6)  * 256 + bb] = nn.x;
    P.FPbuf[(frag * 12 + 7)  * 256 + bb] = nn.y;
    P.FPbuf[(frag * 12 + 8)  * 256 + bb] = nn.z;
    P.FPbuf[(frag * 12 + 9)  * 256 + bb] = C.x;
    P.FPbuf[(frag * 12 + 10) * 256 + bb] = C.y;
    P.FPbuf[(frag * 12 + 11) * 256 + bb] = C.z;
}

// ======== carry: rotation-composition over fragment constants (LDS-staged) ====
__global__ __launch_bounds__(256) void carry_kernel(KParams P) {
    __shared__ float S[384][16];
    const int tid  = threadIdx.x;
    const int base = blockIdx.x * 16;
    for (int i = tid; i < 384 * 16; i += 256) {
        int row = i >> 4, col = i & 15;
        S[row][col] = P.FPbuf[row * 256 + base + col];
    }
    __syncthreads();
    if (tid < 16) {
        int bb = base + tid;
        float3 ob = make_float3(1.f, 0.f, 0.f);
        float3 om = make_float3(0.f, 1.f, 0.f);
        float3 on = make_float3(0.f, 0.f, 1.f);
        float3 c  = make_float3(0.f, 0.f, 0.f);
        for (int f = 0; f < 32; ++f) {
            int fb = (f * 256 + bb) * 3;
            P.frames[fb + 0] = make_float4(ob.x, ob.y, ob.z, om.x);
            P.frames[fb + 1] = make_float4(om.y, om.z, on.x, on.y);
            P.frames[fb + 2] = make_float4(on.z, c.x, c.y, c.z);

            int r0 = f * 12;
            float3 Fb = make_float3(S[r0+0][tid], S[r0+1][tid], S[r0+2][tid]);
            float3 Fm = make_float3(S[r0+3][tid], S[r0+4][tid], S[r0+5][tid]);
            float3 Fn = make_float3(S[r0+6][tid], S[r0+7][tid], S[r0+8][tid]);
            float3 p  = make_float3(S[r0+9][tid], S[r0+10][tid], S[r0+11][tid]);

            float3 nb = make_float3(
                fmaf(ob.x,Fb.x, fmaf(om.x,Fb.y, on.x*Fb.z)),
                fmaf(ob.y,Fb.x, fmaf(om.y,Fb.y, on.y*Fb.z)),
                fmaf(ob.z,Fb.x, fmaf(om.z,Fb.y, on.z*Fb.z)));
            float3 nm = make_float3(
                fmaf(ob.x,Fm.x, fmaf(om.x,Fm.y, on.x*Fm.z)),
                fmaf(ob.y,Fm.x, fmaf(om.y,Fm.y, on.y*Fm.z)),
                fmaf(ob.z,Fm.x, fmaf(om.z,Fm.y, on.z*Fm.z)));
            float3 nn2 = make_float3(
                fmaf(ob.x,Fn.x, fmaf(om.x,Fn.y, on.x*Fn.z)),
                fmaf(ob.y,Fn.x, fmaf(om.y,Fn.y, on.y*Fn.z)),
                fmaf(ob.z,Fn.x, fmaf(om.z,Fn.y, on.z*Fn.z)));
            float3 nc = make_float3(
                fmaf(ob.x,p.x, fmaf(om.x,p.y, fmaf(on.x,p.z, c.x))),
                fmaf(ob.y,p.x, fmaf(om.y,p.y, fmaf(on.y,p.z, c.y))),
                fmaf(ob.z,p.x, fmaf(om.z,p.y, fmaf(on.z,p.z, c.z))));
            ob = nb; om = nm; on = nn2; c = nc;
        }
    }
}

// ======== apply: 4 rows/block; LDS-staged coalesced output ========
__global__ __launch_bounds__(256) void apply_kernel(KParams P) {
    __shared__ float sm[768];
    const int bb = threadIdx.x;
    #pragma unroll 1
    for (int i = 0; i < 4; ++i) {
        const int row  = blockIdx.x * 4 + i;
        const int frag = row / 96;

        float fx = P.fragbuf[(row * 3 + 0) * 256 + bb];
        float fy = P.fragbuf[(row * 3 + 1) * 256 + bb];
        float fz = P.fragbuf[(row * 3 + 2) * 256 + bb];

        int fb = (frag * 256 + bb) * 3;
        float4 f0 = P.frames[fb + 0];
        float4 f1 = P.frames[fb + 1];
        float4 f2 = P.frames[fb + 2];

        float ox = f2.y + f0.x * fx + f0.w * fy + f1.z * fz;
        float oy = f2.z + f0.y * fx + f1.x * fy + f1.w * fz;
        float oz = f2.w + f0.z * fx + f1.y * fy + f2.x * fz;

        __syncthreads();   // prior iteration's sm reads complete
        sm[bb * 3 + 0] = ox;
        sm[bb * 3 + 1] = oy;
        sm[bb * 3 + 2] = oz;
        __syncthreads();

        int base = row * 768;
        P.out[base + bb]       = sm[bb];
        P.out[base + 256 + bb] = sm[256 + bb];
        P.out[base + 512 + bb] = sm[512 + bb];
    }
}

// ======== host launch: 5-dispatch path (coop fusion measured 2.3x worse:
// grid.sync ~90us each on 8-XCD MI355X — r10) ========
extern "C" void kernel_launch(void* const* d_in, const int* in_sizes, int n_in,
                              void* d_out, int out_size, void* d_ws, size_t ws_size,
                              hipStream_t stream) {
    float* ws      = (float*)d_ws;
    float* kmerT   = ws;                       // 10648*64 = 681472
    float* seqT    = kmerT + 681472;           // 1280
    float* srf_t   = seqT + 1280;              // 2359296
    float* fragbuf = srf_t + 2359296;          // 2359296
    float* frames  = fragbuf + 2359296;        // 98304 (float4-accessed)
    float* FPbuf   = frames + 98304;           // 98304

    // split weight tables alias fragbuf (tables writes -> mlp reads -> extend
    // overwrites; strictly ordered by kernel boundaries)
    unsigned short* WeTH  = (unsigned short*)fragbuf;
    unsigned short* WeTL  = WeTH + 4096;
    unsigned short* W0pTH = WeTL + 4096;
    unsigned short* W0pTL = W0pTH + 2048;
    unsigned short* W1TH  = W0pTL + 2048;
    unsigned short* W1TL  = W1TH + 1024;

    KParams P;
    P.seq  = (const int*)d_in[0];
    P.kmer = (const int*)d_in[1];
    P.pssm = (const float*)d_in[2];
    P.se   = (const float*)d_in[4];
    P.emb  = (const float*)d_in[5];
    P.W0   = (const float*)d_in[6];
    P.b0   = (const float*)d_in[7];
    P.We   = (const float*)d_in[8];
    P.be   = (const float*)d_in[9];
    P.W1   = (const float*)d_in[10];
    P.b1   = (const float*)d_in[11];
    P.kmerT = kmerT; P.seqT = seqT; P.srf_t = srf_t; P.fragbuf = fragbuf;
    P.frames = (float4*)frames; P.FPbuf = FPbuf; P.out = (float*)d_out;
    P.WeTH = WeTH; P.WeTL = WeTL; P.W0pTH = W0pTH; P.W0pTL = W0pTL;
    P.W1TH = W1TH; P.W1TL = W1TL;

    hipLaunchKernelGGL(tables_kernel, dim3(173),  dim3(256), 0, stream, P);
    hipLaunchKernelGGL(mlp_kernel,    dim3(4096), dim3(256), 0, stream, P);
    hipLaunchKernelGGL(extend_kernel, dim3(128),  dim3(64),  0, stream, P);
    hipLaunchKernelGGL(carry_kernel,  dim3(16),   dim3(256), 0, stream, P);
    hipLaunchKernelGGL(apply_kernel,  dim3(768),  dim3(256), 0, stream, P);
}

// Round 5
// 192.132 us; speedup vs baseline: 1.1867x; 1.0290x over previous
//
#include <hip/hip_runtime.h>
#include <math.h>

typedef short bf16x8 __attribute__((ext_vector_type(8)));
typedef float f32x4  __attribute__((ext_vector_type(4)));

// round-to-nearest-even float -> bf16 bits
__device__ __forceinline__ unsigned short f2bf(float x) {
    unsigned int u = __float_as_uint(x);
    return (unsigned short)((u + 0x7FFFu + ((u >> 16) & 1u)) >> 16);
}
__device__ __forceinline__ float bf2f(unsigned short h) {
    return __uint_as_float(((unsigned int)h) << 16);
}
// RNE split (precompute path)
__device__ __forceinline__ void split2(float x, unsigned short& h, unsigned short& l) {
    h = f2bf(x);
    l = f2bf(x - bf2f(h));
}
// truncation split (hot path): hi = trunc(x), lo = RNE(x-hi); combined rel err ~2^-17
__device__ __forceinline__ void split2t(float x, unsigned short& h, unsigned short& l) {
    unsigned int u = __float_as_uint(x);
    h = (unsigned short)(u >> 16);
    float r = x - __uint_as_float(u & 0xFFFF0000u);
    l = f2bf(r);
}

// XOR-swizzled H index (shorts): stride 64 shorts (128 B rows), rows 0..15.
// Bank analysis: row stride = 32 dwords == 0 mod 32, so bank is set by the 16B
// chunk; chunk' = chunk ^ (row&7) spreads a b128 column read across all banks
// (<=2-way = free). This exact access family measured ZERO conflicts in r16.
__device__ __forceinline__ int hsw(int row, int col) {
    return (row << 6) + ((((col >> 3) ^ (row & 7)) << 3) | (col & 7));
}

__device__ __forceinline__ float inv_norm3(float x, float y, float z) {
    float d = fmaf(x, x, fmaf(y, y, z * z));
    return rsqrtf(fmaxf(d, 1e-24f));
}
__device__ __forceinline__ float3 f3sub(float3 a, float3 b) {
    return make_float3(a.x - b.x, a.y - b.y, a.z - b.z);
}
__device__ __forceinline__ float3 f3cross(float3 a, float3 b) {
    return make_float3(a.y * b.z - a.z * b.y,
                       a.z * b.x - a.x * b.z,
                       a.x * b.y - a.y * b.x);
}
// NeRF frame, parallel normalizations (n from unnormalized w: same direction)
__device__ __forceinline__ void nerf_frame(const float3& A, const float3& Bv,
                                           const float3& C, float3& bc,
                                           float3& n, float3& m3) {
    float3 w  = f3sub(C, Bv);
    float3 v  = f3sub(Bv, A);
    float3 cr = f3cross(v, w);
    float iw = inv_norm3(w.x, w.y, w.z);
    float ic = inv_norm3(cr.x, cr.y, cr.z);
    bc = make_float3(w.x * iw, w.y * iw, w.z * iw);
    n  = make_float3(cr.x * ic, cr.y * ic, cr.z * ic);
    m3 = f3cross(n, bc);
}
__device__ __forceinline__ float3 nerf_place(const float3& C, const float3& bc,
                                             const float3& m3, const float3& n,
                                             float tx, float ty, float tz) {
    return make_float3(
        fmaf(m3.x, ty, fmaf(bc.x, tx, fmaf(n.x, tz, C.x))),
        fmaf(m3.y, ty, fmaf(bc.y, tx, fmaf(n.y, tz, C.y))),
        fmaf(m3.z, ty, fmaf(bc.z, tx, fmaf(n.z, tz, C.z))));
}

struct KParams {
    const int* seq; const int* kmer; const float* pssm;
    const float* se; const float* emb;
    const float* W0; const float* b0; const float* We; const float* be;
    const float* W1; const float* b1;
    float* kmerT; float* seqT; float* srf_t; float* fragbuf;
    float4* frames; float* FPbuf; float* out;
    unsigned short *WeTH, *WeTL, *W0pTH, *W0pTL, *W1TH, *W1TL;
};

// ======== tables: kmerT via split-bf16 MFMA (vector loads), seqT, weight tables
__global__ __launch_bounds__(256) void tables_kernel(KParams P) {
    const int tid = threadIdx.x;
    const int vb  = blockIdx.x;
    if (vb < 167) {
        const int lane = tid & 63;
        const int wv   = __builtin_amdgcn_readfirstlane(tid >> 6);
        const int q    = lane >> 4;
        const int c16  = lane & 15;
        const int r0   = vb * 64;
        const int n    = wv * 16 + c16;

        bf16x8 BH[8], BL[8];
        #pragma unroll
        for (int kt8 = 0; kt8 < 8; ++kt8)
            #pragma unroll
            for (int j = 0; j < 8; ++j) {
                float w = P.W0[(16 + kt8 * 32 + q * 8 + j) * 64 + n];
                unsigned short h, l; split2t(w, h, l);
                BH[kt8][j] = (short)h; BL[kt8][j] = (short)l;
            }
        f32x4 acc[4];
        #pragma unroll
        for (int t = 0; t < 4; ++t) acc[t] = (f32x4){0.f, 0.f, 0.f, 0.f};
        #pragma unroll
        for (int kt8 = 0; kt8 < 8; ++kt8) {
            #pragma unroll
            for (int t = 0; t < 4; ++t) {
                int rr = r0 + t * 16 + c16;
                if (rr > 10647) rr = 10647;
                const float* ap = P.emb + rr * 256 + kt8 * 32 + q * 8;
                float4 a0 = *(const float4*)ap;
                float4 a1 = *(const float4*)(ap + 4);
                bf16x8 ah, al;
                unsigned short h, l;
                split2t(a0.x, h, l); ah[0] = (short)h; al[0] = (short)l;
                split2t(a0.y, h, l); ah[1] = (short)h; al[1] = (short)l;
                split2t(a0.z, h, l); ah[2] = (short)h; al[2] = (short)l;
                split2t(a0.w, h, l); ah[3] = (short)h; al[3] = (short)l;
                split2t(a1.x, h, l); ah[4] = (short)h; al[4] = (short)l;
                split2t(a1.y, h, l); ah[5] = (short)h; al[5] = (short)l;
                split2t(a1.z, h, l); ah[6] = (short)h; al[6] = (short)l;
                split2t(a1.w, h, l); ah[7] = (short)h; al[7] = (short)l;
                acc[t] = __builtin_amdgcn_mfma_f32_16x16x32_bf16(ah, BH[kt8], acc[t], 0, 0, 0);
                acc[t] = __builtin_amdgcn_mfma_f32_16x16x32_bf16(al, BH[kt8], acc[t], 0, 0, 0);
                acc[t] = __builtin_amdgcn_mfma_f32_16x16x32_bf16(ah, BL[kt8], acc[t], 0, 0, 0);
            }
        }
        #pragma unroll
        for (int t = 0; t < 4; ++t)
            #pragma unroll
            for (int r = 0; r < 4; ++r) {
                int row = r0 + t * 16 + q * 4 + r;
                if (row < 10648) P.kmerT[row * 64 + n] = acc[t][r];
            }
    } else if (vb < 172) {
        // seqT[r][j] = seq_embed[r]@W0[0:16] + b0[j] + 0.5*sum_c W0p[c][j]
        int e = (vb - 167) * 256 + tid;
        int r = e >> 6, j = e & 63;
        float acc = P.b0[j];
        #pragma unroll
        for (int k = 0; k < 16; ++k)
            acc = fmaf(P.se[r * 16 + k], P.W0[k * 64 + j], acc);
        float cs = 0.f;
        #pragma unroll
        for (int c = 0; c < 21; ++c) cs += P.W0[(272 + c) * 64 + j];
        P.seqT[r * 64 + j] = acc + 0.5f * cs;
    } else {
        #pragma unroll
        for (int i = 0; i < 16; ++i) {
            int e = i * 256 + tid;
            int k = e >> 6, n = e & 63;
            unsigned short h, l; split2(P.We[k * 64 + n], h, l);
            P.WeTH[n * 64 + k] = h; P.WeTL[n * 64 + k] = l;
        }
        #pragma unroll
        for (int i = 0; i < 8; ++i) {
            int e = i * 256 + tid;
            int k = e >> 6, n = e & 63;
            float w = (k < 21) ? P.W0[(272 + k) * 64 + n] : 0.f;
            unsigned short h, l; split2(w, h, l);
            P.W0pTH[n * 32 + k] = h; P.W0pTL[n * 32 + k] = l;
        }
        #pragma unroll
        for (int i = 0; i < 4; ++i) {
            int e = i * 256 + tid;
            int k = e >> 4, c = e & 15;
            float w = (c < 9) ? P.W1[k * 9 + c] : 0.f;
            unsigned short h, l; split2(w, h, l);
            P.W1TH[c * 64 + k] = h; P.W1TL[c * 64 + k] = l;
        }
    }
}

// ======== split-bf16 MFMA MLP — r17: M=16 micro-blocks, 8 blocks/CU ==========
// Accumulated evidence (r12-r16): conflicts off critical path; occupancy knobs
// inert; M-split and staging-removal both regress. Diagnosis: ~70% of SIMD
// issue slots idle because all 4 waves of a block stall together at 4 lockstep
// phase boundaries with only ~2.9 correlated blocks/CU of cover.
// r17: keep the r14 wave role EXACTLY (N-split, 10 weight frags = 40 VGPR in
// regs), but shrink the block M-tile 64 -> 16 (one 16x16 D-tile per wave per
// layer, grid 16384). Per-wave state shrinks (acc 16->4, g 16->4, no pa[4]
// array, W1 loaded only in head) -> target VGPR <= 64 so launch_bounds(256,8)
// gives 8 resident blocks/CU (LDS 8KiB/block, cap 19; wave-slot cap 8):
// each barrier stalls a 4-wave group while ~28 other waves at random phase
// offsets keep the SIMDs fed. Same per-element values + accumulation order ->
// bit-identical output. Falsifiers: WRITE_SIZE balloon = spill (relax bounds);
// occupancy stuck ~35% = cover theory dead.
__global__ __launch_bounds__(256, 8) void mlp_kernel(KParams P) {
    __shared__ __align__(16) unsigned char SMEM[8192];
    unsigned short* Hah = (unsigned short*)(SMEM);            // 16x64 swizzled, 2048B
    unsigned short* Hal = (unsigned short*)(SMEM + 2048);
    unsigned short* Hbh = (unsigned short*)(SMEM + 4096);
    unsigned short* Hbl = (unsigned short*)(SMEM + 6144);
    // pssm staging overlays Hb (dead until L1 stores; Pp dead after L0 reads,
    // and the barrier after L0's Ha stores orders Pp-reads before Hb-writes)
    unsigned short (*Pph)[40] = (unsigned short (*)[40])(SMEM + 4096);
    unsigned short (*Ppl)[40] = (unsigned short (*)[40])(SMEM + 4096 + 1280);

    const int tid  = threadIdx.x;
    const int lane = tid & 63;
    const int wv   = __builtin_amdgcn_readfirstlane(tid >> 6);
    const int q    = lane >> 4;
    const int c16  = lane & 15;
    const int m0   = blockIdx.x * 16;
    const int n    = wv * 16 + c16;

    // ---- indices: direct coalesced loads (16 distinct dwords/wave, L1
    //      broadcast across q-groups); gathers issue immediately ----
    int sidx[4], kidx[4];
    #pragma unroll
    for (int r = 0; r < 4; ++r) {
        sidx[r] = P.seq[m0 + q * 4 + r];
        kidx[r] = P.kmer[m0 + q * 4 + r];
    }
    float g[4];
    #pragma unroll
    for (int r = 0; r < 4; ++r)
        g[r] = P.seqT[sidx[r] * 64 + n] + P.kmerT[kidx[r] * 64 + n];

    // ---- stage 16 pssm rows (centered, trunc-split); division-free:
    //      thread (row=tid>>4, c=tid&15) covers cols {c, 16+c(<21), 21+c(<32)}
    {
        const int row_s = tid >> 4;
        const int c_s   = tid & 15;
        const float* pr = P.pssm + (m0 + row_s) * 21;
        unsigned short h, l;
        float v = pr[c_s] - 0.5f;
        split2t(v, h, l);
        Pph[row_s][c_s] = h; Ppl[row_s][c_s] = l;
        if (c_s < 5) {
            float v2 = pr[16 + c_s] - 0.5f;
            split2t(v2, h, l);
            Pph[row_s][16 + c_s] = h; Ppl[row_s][16 + c_s] = l;
        }
        if (c_s < 11) {
            Pph[row_s][21 + c_s] = 0; Ppl[row_s][21 + c_s] = 0;
        }
    }

    // ---- weight fragments + bias (L1/L2-hot 16B loads; W1 deferred to head)
    bf16x8 WeH[2], WeL[2], W0H, W0L;
    #pragma unroll
    for (int kk = 0; kk < 2; ++kk) {
        WeH[kk] = *(const bf16x8*)(P.WeTH + n * 64 + kk * 32 + q * 8);
        WeL[kk] = *(const bf16x8*)(P.WeTL + n * 64 + kk * 32 + q * 8);
    }
    W0H = *(const bf16x8*)(P.W0pTH + n * 32 + q * 8);
    W0L = *(const bf16x8*)(P.W0pTL + n * 32 + q * 8);
    const float be_n = P.be[n];
    __syncthreads();   // pssm staged (cross-wave rows)

    // ---- layer 0: one 16x16 tile; zero-init MFMA, add gathers late ----
    {
        bf16x8 pah = *(const bf16x8*)&Pph[c16][q * 8];
        bf16x8 pal = *(const bf16x8*)&Ppl[c16][q * 8];
        f32x4 a0 = (f32x4){0.f, 0.f, 0.f, 0.f};
        a0 = __builtin_amdgcn_mfma_f32_16x16x32_bf16(pah, W0H, a0, 0, 0, 0);
        a0 = __builtin_amdgcn_mfma_f32_16x16x32_bf16(pal, W0H, a0, 0, 0, 0);
        a0 = __builtin_amdgcn_mfma_f32_16x16x32_bf16(pah, W0L, a0, 0, 0, 0);
        #pragma unroll
        for (int r = 0; r < 4; ++r) {
            unsigned short h, l; split2t(a0[r] + g[r], h, l);
            Hah[hsw(q * 4 + r, n)] = h;
            Hal[hsw(q * 4 + r, n)] = l;
        }
    }
    __syncthreads();   // h0 ready; Pp reads done -> Hb overlay reusable

    // ---- layer 1: Ha -> Hb (relu) ----
    {
        f32x4 a1 = (f32x4){be_n, be_n, be_n, be_n};
        #pragma unroll
        for (int kk = 0; kk < 2; ++kk) {
            bf16x8 ah = *(const bf16x8*)&Hah[hsw(c16, kk * 32 + q * 8)];
            bf16x8 al = *(const bf16x8*)&Hal[hsw(c16, kk * 32 + q * 8)];
            a1 = __builtin_amdgcn_mfma_f32_16x16x32_bf16(ah, WeH[kk], a1, 0, 0, 0);
            a1 = __builtin_amdgcn_mfma_f32_16x16x32_bf16(al, WeH[kk], a1, 0, 0, 0);
            a1 = __builtin_amdgcn_mfma_f32_16x16x32_bf16(ah, WeL[kk], a1, 0, 0, 0);
        }
        #pragma unroll
        for (int r = 0; r < 4; ++r) {
            unsigned short h, l; split2t(fmaxf(a1[r], 0.f), h, l);
            Hbh[hsw(q * 4 + r, n)] = h;
            Hbl[hsw(q * 4 + r, n)] = l;
        }
    }
    __syncthreads();

    // ---- layer 2: Hb -> Ha (relu) ----
    {
        f32x4 a2 = (f32x4){be_n, be_n, be_n, be_n};
        #pragma unroll
        for (int kk = 0; kk < 2; ++kk) {
            bf16x8 ah = *(const bf16x8*)&Hbh[hsw(c16, kk * 32 + q * 8)];
            bf16x8 al = *(const bf16x8*)&Hbl[hsw(c16, kk * 32 + q * 8)];
            a2 = __builtin_amdgcn_mfma_f32_16x16x32_bf16(ah, WeH[kk], a2, 0, 0, 0);
            a2 = __builtin_amdgcn_mfma_f32_16x16x32_bf16(al, WeH[kk], a2, 0, 0, 0);
            a2 = __builtin_amdgcn_mfma_f32_16x16x32_bf16(ah, WeL[kk], a2, 0, 0, 0);
        }
        #pragma unroll
        for (int r = 0; r < 4; ++r) {
            unsigned short h, l; split2t(fmaxf(a2[r], 0.f), h, l);
            Hah[hsw(q * 4 + r, n)] = h;
            Hal[hsw(q * 4 + r, n)] = l;
        }
    }
    __syncthreads();

    // ---- head: single tile -> wave 0 only (others retire, freeing slots) ----
    if (wv == 0) {
        bf16x8 W1H[2], W1L[2];
        #pragma unroll
        for (int kk = 0; kk < 2; ++kk) {
            W1H[kk] = *(const bf16x8*)(P.W1TH + c16 * 64 + kk * 32 + q * 8);
            W1L[kk] = *(const bf16x8*)(P.W1TL + c16 * 64 + kk * 32 + q * 8);
        }
        const float b1h = (c16 < 9) ? P.b1[c16] : 0.f;
        f32x4 ah4 = (f32x4){b1h, b1h, b1h, b1h};
        #pragma unroll
        for (int kk = 0; kk < 2; ++kk) {
            bf16x8 ah = *(const bf16x8*)&Hah[hsw(c16, kk * 32 + q * 8)];
            bf16x8 al = *(const bf16x8*)&Hal[hsw(c16, kk * 32 + q * 8)];
            ah4 = __builtin_amdgcn_mfma_f32_16x16x32_bf16(ah, W1H[kk], ah4, 0, 0, 0);
            ah4 = __builtin_amdgcn_mfma_f32_16x16x32_bf16(al, W1H[kk], ah4, 0, 0, 0);
            ah4 = __builtin_amdgcn_mfma_f32_16x16x32_bf16(ah, W1L[kk], ah4, 0, 0, 0);
        }
        if (c16 < 9) {
            #pragma unroll
            for (int r = 0; r < 4; ++r) {
                int pos = m0 + q * 4 + r;
                int l = pos >> 8, b = pos & 255;
                P.srf_t[(l * 9 + c16) * 256 + b] = ah4[r];
            }
        }
    }
}

// ======== extend: depth-3 prefetch; emits per-fragment frame + endpoint ========
__global__ __launch_bounds__(64) void extend_kernel(KParams P) {
    int frag = blockIdx.x >> 2;
    int bb   = ((blockIdx.x & 3) << 6) + threadIdx.x;

    float3 A  = make_float3(-0.70710678118654752f, 1.22474487139158905f, 0.f);
    float3 Bv = make_float3(-1.41421356237309505f, 0.f, 0.f);
    float3 C  = make_float3(0.f, 0.f, 0.f);

    float ct0[9], ct1[9], ct2[9], ct3[9];
    #pragma unroll
    for (int m = 0; m < 9; ++m) {
        ct0[m] = P.srf_t[((frag * 32 + 0) * 9 + m) * 256 + bb];
        ct1[m] = P.srf_t[((frag * 32 + 1) * 9 + m) * 256 + bb];
        ct2[m] = P.srf_t[((frag * 32 + 2) * 9 + m) * 256 + bb];
    }
    for (int ll = 0; ll < 32; ++ll) {
        if (ll < 29) {
            #pragma unroll
            for (int m = 0; m < 9; ++m)
                ct3[m] = P.srf_t[((frag * 32 + ll + 3) * 9 + m) * 256 + bb];
        } else {
            #pragma unroll
            for (int m = 0; m < 9; ++m) ct3[m] = 0.f;
        }
        #pragma unroll
        for (int s3 = 0; s3 < 3; ++s3) {
            float3 bc, nn, m3;
            nerf_frame(A, Bv, C, bc, nn, m3);
            float3 d = nerf_place(C, bc, m3, nn,
                                  ct0[3 * s3 + 0], ct0[3 * s3 + 1], ct0[3 * s3 + 2]);
            int row = frag * 96 + ll * 3 + s3;
            P.fragbuf[(row * 3 + 0) * 256 + bb] = d.x;
            P.fragbuf[(row * 3 + 1) * 256 + bb] = d.y;
            P.fragbuf[(row * 3 + 2) * 256 + bb] = d.z;
            A = Bv; Bv = C; C = d;
        }
        #pragma unroll
        for (int m = 0; m < 9; ++m) { ct0[m] = ct1[m]; ct1[m] = ct2[m]; ct2[m] = ct3[m]; }
    }
    float3 bc, nn, m3;
    nerf_frame(A, Bv, C, bc, nn, m3);
    P.FPbuf[(frag * 12 + 0)  * 256 + bb] = bc.x;
    P.FPbuf[(frag * 12 + 1)  * 256 + bb] = bc.y;
    P.FPbuf[(frag * 12 + 2)  * 256 + bb] = bc.z;
    P.FPbuf[(frag * 12 + 3)  * 256 + bb] = m3.x;
    P.FPbuf[(frag * 12 + 4)  * 256 + bb] = m3.y;
    P.FPbuf[(frag * 12 + 5)  * 256 + bb] = m3.z;
    P.FPbuf[(frag * 12 + 6)  * 256 + bb] = nn.x;
    P.FPbuf[(frag * 12 + 7)  * 256 + bb] = nn.y;
    P.FPbuf[(frag * 12 + 8)  * 256 + bb] = nn.z;
    P.FPbuf[(frag * 12 + 9)  * 256 + bb] = C.x;
    P.FPbuf[(frag * 12 + 10) * 256 + bb] = C.y;
    P.FPbuf[(frag * 12 + 11) * 256 + bb] = C.z;
}

// ======== carry: rotation-composition over fragment constants (LDS-staged) ====
__global__ __launch_bounds__(256) void carry_kernel(KParams P) {
    __shared__ float S[384][16];
    const int tid  = threadIdx.x;
    const int base = blockIdx.x * 16;
    for (int i = tid; i < 384 * 16; i += 256) {
        int row = i >> 4, col = i & 15;
        S[row][col] = P.FPbuf[row * 256 + base + col];
    }
    __syncthreads();
    if (tid < 16) {
        int bb = base + tid;
        float3 ob = make_float3(1.f, 0.f, 0.f);
        float3 om = make_float3(0.f, 1.f, 0.f);
        float3 on = make_float3(0.f, 0.f, 1.f);
        float3 c  = make_float3(0.f, 0.f, 0.f);
        for (int f = 0; f < 32; ++f) {
            int fb = (f * 256 + bb) * 3;
            P.frames[fb + 0] = make_float4(ob.x, ob.y, ob.z, om.x);
            P.frames[fb + 1] = make_float4(om.y, om.z, on.x, on.y);
            P.frames[fb + 2] = make_float4(on.z, c.x, c.y, c.z);

            int r0 = f * 12;
            float3 Fb = make_float3(S[r0+0][tid], S[r0+1][tid], S[r0+2][tid]);
            float3 Fm = make_float3(S[r0+3][tid], S[r0+4][tid], S[r0+5][tid]);
            float3 Fn = make_float3(S[r0+6][tid], S[r0+7][tid], S[r0+8][tid]);
            float3 p  = make_float3(S[r0+9][tid], S[r0+10][tid], S[r0+11][tid]);

            float3 nb = make_float3(
                fmaf(ob.x,Fb.x, fmaf(om.x,Fb.y, on.x*Fb.z)),
                fmaf(ob.y,Fb.x, fmaf(om.y,Fb.y, on.y*Fb.z)),
                fmaf(ob.z,Fb.x, fmaf(om.z,Fb.y, on.z*Fb.z)));
            float3 nm = make_float3(
                fmaf(ob.x,Fm.x, fmaf(om.x,Fm.y, on.x*Fm.z)),
                fmaf(ob.y,Fm.x, fmaf(om.y,Fm.y, on.y*Fm.z)),
                fmaf(ob.z,Fm.x, fmaf(om.z,Fm.y, on.z*Fm.z)));
            float3 nn2 = make_float3(
                fmaf(ob.x,Fn.x, fmaf(om.x,Fn.y, on.x*Fn.z)),
                fmaf(ob.y,Fn.x, fmaf(om.y,Fn.y, on.y*Fn.z)),
                fmaf(ob.z,Fn.x, fmaf(om.z,Fn.y, on.z*Fn.z)));
            float3 nc = make_float3(
                fmaf(ob.x,p.x, fmaf(om.x,p.y, fmaf(on.x,p.z, c.x))),
                fmaf(ob.y,p.x, fmaf(om.y,p.y, fmaf(on.y,p.z, c.y))),
                fmaf(ob.z,p.x, fmaf(om.z,p.y, fmaf(on.z,p.z, c.z))));
            ob = nb; om = nm; on = nn2; c = nc;
        }
    }
}

// ======== apply: 4 rows/block; LDS-staged coalesced output ========
__global__ __launch_bounds__(256) void apply_kernel(KParams P) {
    __shared__ float sm[768];
    const int bb = threadIdx.x;
    #pragma unroll 1
    for (int i = 0; i < 4; ++i) {
        const int row  = blockIdx.x * 4 + i;
        const int frag = row / 96;

        float fx = P.fragbuf[(row * 3 + 0) * 256 + bb];
        float fy = P.fragbuf[(row * 3 + 1) * 256 + bb];
        float fz = P.fragbuf[(row * 3 + 2) * 256 + bb];

        int fb = (frag * 256 + bb) * 3;
        float4 f0 = P.frames[fb + 0];
        float4 f1 = P.frames[fb + 1];
        float4 f2 = P.frames[fb + 2];

        float ox = f2.y + f0.x * fx + f0.w * fy + f1.z * fz;
        float oy = f2.z + f0.y * fx + f1.x * fy + f1.w * fz;
        float oz = f2.w + f0.z * fx + f1.y * fy + f2.x * fz;

        __syncthreads();   // prior iteration's sm reads complete
        sm[bb * 3 + 0] = ox;
        sm[bb * 3 + 1] = oy;
        sm[bb * 3 + 2] = oz;
        __syncthreads();

        int base = row * 768;
        P.out[base + bb]       = sm[bb];
        P.out[base + 256 + bb] = sm[256 + bb];
        P.out[base + 512 + bb] = sm[512 + bb];
    }
}

// ======== host launch: 5-dispatch path (coop fusion measured 2.3x worse:
// grid.sync ~90us each on 8-XCD MI355X — r10) ========
extern "C" void kernel_launch(void* const* d_in, const int* in_sizes, int n_in,
                              void* d_out, int out_size, void* d_ws, size_t ws_size,
                              hipStream_t stream) {
    float* ws      = (float*)d_ws;
    float* kmerT   = ws;                       // 10648*64 = 681472
    float* seqT    = kmerT + 681472;           // 1280
    float* srf_t   = seqT + 1280;              // 2359296
    float* fragbuf = srf_t + 2359296;          // 2359296
    float* frames  = fragbuf + 2359296;        // 98304 (float4-accessed)
    float* FPbuf   = frames + 98304;           // 98304

    // split weight tables alias fragbuf (tables writes -> mlp reads -> extend
    // overwrites; strictly ordered by kernel boundaries)
    unsigned short* WeTH  = (unsigned short*)fragbuf;
    unsigned short* WeTL  = WeTH + 4096;
    unsigned short* W0pTH = WeTL + 4096;
    unsigned short* W0pTL = W0pTH + 2048;
    unsigned short* W1TH  = W0pTL + 2048;
    unsigned short* W1TL  = W1TH + 1024;

    KParams P;
    P.seq  = (const int*)d_in[0];
    P.kmer = (const int*)d_in[1];
    P.pssm = (const float*)d_in[2];
    P.se   = (const float*)d_in[4];
    P.emb  = (const float*)d_in[5];
    P.W0   = (const float*)d_in[6];
    P.b0   = (const float*)d_in[7];
    P.We   = (const float*)d_in[8];
    P.be   = (const float*)d_in[9];
    P.W1   = (const float*)d_in[10];
    P.b1   = (const float*)d_in[11];
    P.kmerT = kmerT; P.seqT = seqT; P.srf_t = srf_t; P.fragbuf = fragbuf;
    P.frames = (float4*)frames; P.FPbuf = FPbuf; P.out = (float*)d_out;
    P.WeTH = WeTH; P.WeTL = WeTL; P.W0pTH = W0pTH; P.W0pTL = W0pTL;
    P.W1TH = W1TH; P.W1TL = W1TL;

    hipLaunchKernelGGL(tables_kernel, dim3(173),   dim3(256), 0, stream, P);
    hipLaunchKernelGGL(mlp_kernel,    dim3(16384), dim3(256), 0, stream, P);
    hipLaunchKernelGGL(extend_kernel, dim3(128),   dim3(64),  0, stream, P);
    hipLaunchKernelGGL(carry_kernel,  dim3(16),    dim3(256), 0, stream, P);
    hipLaunchKernelGGL(apply_kernel,  dim3(768),   dim3(256), 0, stream, P);
}

// Round 6
// 179.761 us; speedup vs baseline: 1.2683x; 1.0688x over previous
//
#include <hip/hip_runtime.h>
#include <math.h>

typedef short bf16x8 __attribute__((ext_vector_type(8)));
typedef float f32x4  __attribute__((ext_vector_type(4)));
typedef unsigned int u32x4 __attribute__((ext_vector_type(4)));

// round-to-nearest-even float -> bf16 bits
__device__ __forceinline__ unsigned short f2bf(float x) {
    unsigned int u = __float_as_uint(x);
    return (unsigned short)((u + 0x7FFFu + ((u >> 16) & 1u)) >> 16);
}
__device__ __forceinline__ float bf2f(unsigned short h) {
    return __uint_as_float(((unsigned int)h) << 16);
}
// RNE split (precompute path)
__device__ __forceinline__ void split2(float x, unsigned short& h, unsigned short& l) {
    h = f2bf(x);
    l = f2bf(x - bf2f(h));
}
// truncation split (hot path): hi = trunc(x), lo = RNE(x-hi); combined rel err ~2^-17
__device__ __forceinline__ void split2t(float x, unsigned short& h, unsigned short& l) {
    unsigned int u = __float_as_uint(x);
    h = (unsigned short)(u >> 16);
    float r = x - __uint_as_float(u & 0xFFFF0000u);
    l = f2bf(r);
}
// packed split: u32 = h | (l<<16) — identical h/l bits as split2t
__device__ __forceinline__ unsigned pack2t(float x) {
    unsigned int u = __float_as_uint(x);
    float r = x - __uint_as_float(u & 0xFFFF0000u);
    return (u >> 16) | ((unsigned)f2bf(r) << 16);
}

// ---- packed-u32 LDS layout with chunk-XOR swizzle -------------------------
// H plane: [64 rows][64 cols] u32 (16 KiB). Dword index:
//   row*64 + ((chunk ^ (row&15))<<2) + (col&3),  chunk = col>>2 (16 chunks).
// Within-chunk order untouched -> b128 reads deliver cols in logical order
// (no operand permutation). Bank check (bank = dwordidx%32, row*64 == 0):
//   writes (col n fixed, rows t*16+q*4+r, instr fixes t,r): bank bits =
//   {(c16>>2)^r, (wv^q)&1, c16&3} -> 32 banks / 64 lanes = 2/bank = free.
//   reads (row=c16, b128): 8 lanes share each 4-bank class * 4 dwords =
//   8 acc/bank = the 1KB/wave minimum. [m136: 2-way free]
__device__ __forceinline__ int hswp(int row, int col) {
    return (row << 6) + ((((col >> 2) ^ (row & 15)) << 2) | (col & 3));
}
// pssm plane: [64 rows][32 cols] u32 (8 KiB), 8 chunks -> XOR row&7
__device__ __forceinline__ int pswp(int row, int col) {
    return (row << 5) + ((((col >> 2) ^ (row & 7)) << 2) | (col & 3));
}

// read 8 packed u32 (cols col0..col0+7) and unpack to h/l bf16x8 fragments.
// 2 x ds_read_b128 + 8 x v_perm_b32 (the packing halves WRITE count; reads
// carry both planes in the same 2 instructions as before).
__device__ __forceinline__ void rd8h(const unsigned* Hp, int row, int col0,
                                     bf16x8& ah, bf16x8& al) {
    u32x4 p0 = *(const u32x4*)(Hp + hswp(row, col0));
    u32x4 p1 = *(const u32x4*)(Hp + hswp(row, col0 + 4));
    unsigned a0 = __builtin_amdgcn_perm(p0[1], p0[0], 0x05040100u);
    unsigned a1 = __builtin_amdgcn_perm(p0[3], p0[2], 0x05040100u);
    unsigned a2 = __builtin_amdgcn_perm(p1[1], p1[0], 0x05040100u);
    unsigned a3 = __builtin_amdgcn_perm(p1[3], p1[2], 0x05040100u);
    unsigned b0 = __builtin_amdgcn_perm(p0[1], p0[0], 0x07060302u);
    unsigned b1 = __builtin_amdgcn_perm(p0[3], p0[2], 0x07060302u);
    unsigned b2 = __builtin_amdgcn_perm(p1[3] * 0 + p1[1], p1[0], 0x07060302u);
    unsigned b3 = __builtin_amdgcn_perm(p1[3], p1[2], 0x07060302u);
    u32x4 av = {a0, a1, a2, a3};
    u32x4 bv = {b0, b1, b2, b3};
    ah = __builtin_bit_cast(bf16x8, av);
    al = __builtin_bit_cast(bf16x8, bv);
}
__device__ __forceinline__ void rd8p(const unsigned* Pp, int row, int col0,
                                     bf16x8& ah, bf16x8& al) {
    u32x4 p0 = *(const u32x4*)(Pp + pswp(row, col0));
    u32x4 p1 = *(const u32x4*)(Pp + pswp(row, col0 + 4));
    unsigned a0 = __builtin_amdgcn_perm(p0[1], p0[0], 0x05040100u);
    unsigned a1 = __builtin_amdgcn_perm(p0[3], p0[2], 0x05040100u);
    unsigned a2 = __builtin_amdgcn_perm(p1[1], p1[0], 0x05040100u);
    unsigned a3 = __builtin_amdgcn_perm(p1[3], p1[2], 0x05040100u);
    unsigned b0 = __builtin_amdgcn_perm(p0[1], p0[0], 0x07060302u);
    unsigned b1 = __builtin_amdgcn_perm(p0[3], p0[2], 0x07060302u);
    unsigned b2 = __builtin_amdgcn_perm(p1[1], p1[0], 0x07060302u);
    unsigned b3 = __builtin_amdgcn_perm(p1[3], p1[2], 0x07060302u);
    u32x4 av = {a0, a1, a2, a3};
    u32x4 bv = {b0, b1, b2, b3};
    ah = __builtin_bit_cast(bf16x8, av);
    al = __builtin_bit_cast(bf16x8, bv);
}

__device__ __forceinline__ float inv_norm3(float x, float y, float z) {
    float d = fmaf(x, x, fmaf(y, y, z * z));
    return rsqrtf(fmaxf(d, 1e-24f));
}
__device__ __forceinline__ float3 f3sub(float3 a, float3 b) {
    return make_float3(a.x - b.x, a.y - b.y, a.z - b.z);
}
__device__ __forceinline__ float3 f3cross(float3 a, float3 b) {
    return make_float3(a.y * b.z - a.z * b.y,
                       a.z * b.x - a.x * b.z,
                       a.x * b.y - a.y * b.x);
}
// NeRF frame, parallel normalizations (n from unnormalized w: same direction)
__device__ __forceinline__ void nerf_frame(const float3& A, const float3& Bv,
                                           const float3& C, float3& bc,
                                           float3& n, float3& m3) {
    float3 w  = f3sub(C, Bv);
    float3 v  = f3sub(Bv, A);
    float3 cr = f3cross(v, w);
    float iw = inv_norm3(w.x, w.y, w.z);
    float ic = inv_norm3(cr.x, cr.y, cr.z);
    bc = make_float3(w.x * iw, w.y * iw, w.z * iw);
    n  = make_float3(cr.x * ic, cr.y * ic, cr.z * ic);
    m3 = f3cross(n, bc);
}
__device__ __forceinline__ float3 nerf_place(const float3& C, const float3& bc,
                                             const float3& m3, const float3& n,
                                             float tx, float ty, float tz) {
    return make_float3(
        fmaf(m3.x, ty, fmaf(bc.x, tx, fmaf(n.x, tz, C.x))),
        fmaf(m3.y, ty, fmaf(bc.y, tx, fmaf(n.y, tz, C.y))),
        fmaf(m3.z, ty, fmaf(bc.z, tx, fmaf(n.z, tz, C.z))));
}

struct KParams {
    const int* seq; const int* kmer; const float* pssm;
    const float* se; const float* emb;
    const float* W0; const float* b0; const float* We; const float* be;
    const float* W1; const float* b1;
    float* kmerT; float* seqT; float* srf_t; float* fragbuf;
    float4* frames; float* FPbuf; float* out;
    unsigned short *WeTH, *WeTL, *W0pTH, *W0pTL, *W1TH, *W1TL;
};

// ======== tables: kmerT via split-bf16 MFMA (vector loads), seqT, weight tables
__global__ __launch_bounds__(256) void tables_kernel(KParams P) {
    const int tid = threadIdx.x;
    const int vb  = blockIdx.x;
    if (vb < 167) {
        const int lane = tid & 63;
        const int wv   = __builtin_amdgcn_readfirstlane(tid >> 6);
        const int q    = lane >> 4;
        const int c16  = lane & 15;
        const int r0   = vb * 64;
        const int n    = wv * 16 + c16;

        bf16x8 BH[8], BL[8];
        #pragma unroll
        for (int kt8 = 0; kt8 < 8; ++kt8)
            #pragma unroll
            for (int j = 0; j < 8; ++j) {
                float w = P.W0[(16 + kt8 * 32 + q * 8 + j) * 64 + n];
                unsigned short h, l; split2t(w, h, l);
                BH[kt8][j] = (short)h; BL[kt8][j] = (short)l;
            }
        f32x4 acc[4];
        #pragma unroll
        for (int t = 0; t < 4; ++t) acc[t] = (f32x4){0.f, 0.f, 0.f, 0.f};
        #pragma unroll
        for (int kt8 = 0; kt8 < 8; ++kt8) {
            #pragma unroll
            for (int t = 0; t < 4; ++t) {
                int rr = r0 + t * 16 + c16;
                if (rr > 10647) rr = 10647;
                const float* ap = P.emb + rr * 256 + kt8 * 32 + q * 8;
                float4 a0 = *(const float4*)ap;
                float4 a1 = *(const float4*)(ap + 4);
                bf16x8 ah, al;
                unsigned short h, l;
                split2t(a0.x, h, l); ah[0] = (short)h; al[0] = (short)l;
                split2t(a0.y, h, l); ah[1] = (short)h; al[1] = (short)l;
                split2t(a0.z, h, l); ah[2] = (short)h; al[2] = (short)l;
                split2t(a0.w, h, l); ah[3] = (short)h; al[3] = (short)l;
                split2t(a1.x, h, l); ah[4] = (short)h; al[4] = (short)l;
                split2t(a1.y, h, l); ah[5] = (short)h; al[5] = (short)l;
                split2t(a1.z, h, l); ah[6] = (short)h; al[6] = (short)l;
                split2t(a1.w, h, l); ah[7] = (short)h; al[7] = (short)l;
                acc[t] = __builtin_amdgcn_mfma_f32_16x16x32_bf16(ah, BH[kt8], acc[t], 0, 0, 0);
                acc[t] = __builtin_amdgcn_mfma_f32_16x16x32_bf16(al, BH[kt8], acc[t], 0, 0, 0);
                acc[t] = __builtin_amdgcn_mfma_f32_16x16x32_bf16(ah, BL[kt8], acc[t], 0, 0, 0);
            }
        }
        #pragma unroll
        for (int t = 0; t < 4; ++t)
            #pragma unroll
            for (int r = 0; r < 4; ++r) {
                int row = r0 + t * 16 + q * 4 + r;
                if (row < 10648) P.kmerT[row * 64 + n] = acc[t][r];
            }
    } else if (vb < 172) {
        // seqT[r][j] = seq_embed[r]@W0[0:16] + b0[j] + 0.5*sum_c W0p[c][j]
        int e = (vb - 167) * 256 + tid;
        int r = e >> 6, j = e & 63;
        float acc = P.b0[j];
        #pragma unroll
        for (int k = 0; k < 16; ++k)
            acc = fmaf(P.se[r * 16 + k], P.W0[k * 64 + j], acc);
        float cs = 0.f;
        #pragma unroll
        for (int c = 0; c < 21; ++c) cs += P.W0[(272 + c) * 64 + j];
        P.seqT[r * 64 + j] = acc + 0.5f * cs;
    } else {
        #pragma unroll
        for (int i = 0; i < 16; ++i) {
            int e = i * 256 + tid;
            int k = e >> 6, n = e & 63;
            unsigned short h, l; split2(P.We[k * 64 + n], h, l);
            P.WeTH[n * 64 + k] = h; P.WeTL[n * 64 + k] = l;
        }
        #pragma unroll
        for (int i = 0; i < 8; ++i) {
            int e = i * 256 + tid;
            int k = e >> 6, n = e & 63;
            float w = (k < 21) ? P.W0[(272 + k) * 64 + n] : 0.f;
            unsigned short h, l; split2(w, h, l);
            P.W0pTH[n * 32 + k] = h; P.W0pTL[n * 32 + k] = l;
        }
        #pragma unroll
        for (int i = 0; i < 4; ++i) {
            int e = i * 256 + tid;
            int k = e >> 4, c = e & 15;
            float w = (c < 9) ? P.W1[k * 9 + c] : 0.f;
            unsigned short h, l; split2(w, h, l);
            P.W1TH[c * 64 + k] = h; P.W1TL[c * 64 + k] = l;
        }
    }
}

// ======== split-bf16 MFMA MLP — r18: packed-u32 LDS, halved DS op count ======
// r17 post-mortem: occupancy 70% measured, dur WORSE -> latency cover was
// never the limit. Arithmetic points at the per-CU LDS pipe: r14 issued ~188
// DS ops/wave (~1370 cyc) -> ~37us of pure LDS serialization of the 47.5us.
// r18 = r14 skeleton with DS ops halved:
//  (1) h|l packed into ONE u32 plane (writes 96->48, stage 16->8); reads stay
//      2 x b128 per fragment-pair (carry both halves), consumer unpacks with
//      8 v_perm_b32 -> moves work from the single LDS pipe to 4 VALU SIMDs.
//  (2) chunk-XOR swizzle chunk^=(row&15) on u32 layout: within-chunk order
//      untouched (no operand permutation), writes 2 lanes/bank (free).
//  (3) seq|kmer<<5 packed -> 16 ds_bpermute instead of 32.
// Identical h/l bits feed the identical MFMA sequence -> bit-identical output.
__global__ __launch_bounds__(256, 4) void mlp_kernel(KParams P) {
    __shared__ __align__(16) unsigned SMEMU[8192];   // 32 KiB
    unsigned* Ha = SMEMU;                            // [64][64] u32 packed h|l
    unsigned* Hb = SMEMU + 4096;
    unsigned* Pp = Hb;                               // pssm overlay [64][32] u32

    const int tid  = threadIdx.x;
    const int lane = tid & 63;
    const int wv   = __builtin_amdgcn_readfirstlane(tid >> 6);
    const int q    = lane >> 4;
    const int c16  = lane & 15;
    const int m0   = blockIdx.x * 64;
    const int n    = wv * 16 + c16;

    // ---- indices: one coalesced load per lane, seq|kmer packed into one
    //      dword -> 16 bpermutes (was 32); gathers issue immediately ----
    const int mypack = P.seq[m0 + lane] | (P.kmer[m0 + lane] << 5);
    float g[4][4];
    #pragma unroll
    for (int t = 0; t < 4; ++t)
        #pragma unroll
        for (int r = 0; r < 4; ++r) {
            int src = (t * 16 + q * 4 + r) << 2;
            int v  = __builtin_amdgcn_ds_bpermute(src, mypack);
            int s  = v & 31;
            int km = v >> 5;
            g[t][r] = P.seqT[s * 64 + n] + P.kmerT[km * 64 + n];
        }

    // ---- stage centered pssm (packed trunc-split, swizzled) ----
    for (int i = tid; i < 64 * 21; i += 256) {
        float v = P.pssm[m0 * 21 + i] - 0.5f;
        Pp[pswp(i / 21, i % 21)] = pack2t(v);
    }
    for (int i = tid; i < 64 * 11; i += 256) {
        Pp[pswp(i / 11, 21 + (i % 11))] = 0u;
    }

    // ---- weight fragments + biases (L1/L2-hot 16B loads) ----
    bf16x8 WeH[2], WeL[2], W1H[2], W1L[2], W0H, W0L;
    #pragma unroll
    for (int kk = 0; kk < 2; ++kk) {
        WeH[kk] = *(const bf16x8*)(P.WeTH + n * 64 + kk * 32 + q * 8);
        WeL[kk] = *(const bf16x8*)(P.WeTL + n * 64 + kk * 32 + q * 8);
        W1H[kk] = *(const bf16x8*)(P.W1TH + c16 * 64 + kk * 32 + q * 8);
        W1L[kk] = *(const bf16x8*)(P.W1TL + c16 * 64 + kk * 32 + q * 8);
    }
    W0H = *(const bf16x8*)(P.W0pTH + n * 32 + q * 8);
    W0L = *(const bf16x8*)(P.W0pTL + n * 32 + q * 8);
    const float be_n = P.be[n];
    const float b1h  = (c16 < 9) ? P.b1[c16] : 0.f;
    __syncthreads();

    // ---- layer 0: zero-init MFMA, then add gathers late ----
    f32x4 acc[4];
    #pragma unroll
    for (int t = 0; t < 4; ++t) acc[t] = (f32x4){0.f, 0.f, 0.f, 0.f};
    #pragma unroll
    for (int t = 0; t < 4; ++t) {
        bf16x8 pah, pal;
        rd8p(Pp, t * 16 + c16, q * 8, pah, pal);
        acc[t] = __builtin_amdgcn_mfma_f32_16x16x32_bf16(pah, W0H, acc[t], 0, 0, 0);
        acc[t] = __builtin_amdgcn_mfma_f32_16x16x32_bf16(pal, W0H, acc[t], 0, 0, 0);
        acc[t] = __builtin_amdgcn_mfma_f32_16x16x32_bf16(pah, W0L, acc[t], 0, 0, 0);
    }
    #pragma unroll
    for (int t = 0; t < 4; ++t)
        #pragma unroll
        for (int r = 0; r < 4; ++r)
            Ha[hswp(t * 16 + q * 4 + r, n)] = pack2t(acc[t][r] + g[t][r]);
    __syncthreads();   // h0 ready; Pp reads done -> Hb overlay reusable

    // ---- layer 1: Ha -> Hb (relu) ----
    {
        f32x4 a1[4];
        #pragma unroll
        for (int t = 0; t < 4; ++t) {
            a1[t] = (f32x4){be_n, be_n, be_n, be_n};
            #pragma unroll
            for (int kk = 0; kk < 2; ++kk) {
                bf16x8 ah, al;
                rd8h(Ha, t * 16 + c16, kk * 32 + q * 8, ah, al);
                a1[t] = __builtin_amdgcn_mfma_f32_16x16x32_bf16(ah, WeH[kk], a1[t], 0, 0, 0);
                a1[t] = __builtin_amdgcn_mfma_f32_16x16x32_bf16(al, WeH[kk], a1[t], 0, 0, 0);
                a1[t] = __builtin_amdgcn_mfma_f32_16x16x32_bf16(ah, WeL[kk], a1[t], 0, 0, 0);
            }
        }
        #pragma unroll
        for (int t = 0; t < 4; ++t)
            #pragma unroll
            for (int r = 0; r < 4; ++r)
                Hb[hswp(t * 16 + q * 4 + r, n)] = pack2t(fmaxf(a1[t][r], 0.f));
        __syncthreads();
    }
    // ---- layer 2: Hb -> Ha (relu) ----
    {
        f32x4 a2[4];
        #pragma unroll
        for (int t = 0; t < 4; ++t) {
            a2[t] = (f32x4){be_n, be_n, be_n, be_n};
            #pragma unroll
            for (int kk = 0; kk < 2; ++kk) {
                bf16x8 ah, al;
                rd8h(Hb, t * 16 + c16, kk * 32 + q * 8, ah, al);
                a2[t] = __builtin_amdgcn_mfma_f32_16x16x32_bf16(ah, WeH[kk], a2[t], 0, 0, 0);
                a2[t] = __builtin_amdgcn_mfma_f32_16x16x32_bf16(al, WeH[kk], a2[t], 0, 0, 0);
                a2[t] = __builtin_amdgcn_mfma_f32_16x16x32_bf16(ah, WeL[kk], a2[t], 0, 0, 0);
            }
        }
        #pragma unroll
        for (int t = 0; t < 4; ++t)
            #pragma unroll
            for (int r = 0; r < 4; ++r)
                Ha[hswp(t * 16 + q * 4 + r, n)] = pack2t(fmaxf(a2[t][r], 0.f));
        __syncthreads();
    }
    // ---- head: wave wv does M-tile wv ----
    {
        f32x4 ah4 = (f32x4){b1h, b1h, b1h, b1h};
        #pragma unroll
        for (int kk = 0; kk < 2; ++kk) {
            bf16x8 ah, al;
            rd8h(Ha, wv * 16 + c16, kk * 32 + q * 8, ah, al);
            ah4 = __builtin_amdgcn_mfma_f32_16x16x32_bf16(ah, W1H[kk], ah4, 0, 0, 0);
            ah4 = __builtin_amdgcn_mfma_f32_16x16x32_bf16(al, W1H[kk], ah4, 0, 0, 0);
            ah4 = __builtin_amdgcn_mfma_f32_16x16x32_bf16(ah, W1L[kk], ah4, 0, 0, 0);
        }
        if (c16 < 9) {
            #pragma unroll
            for (int r = 0; r < 4; ++r) {
                int pos = m0 + wv * 16 + q * 4 + r;
                int l = pos >> 8, b = pos & 255;
                P.srf_t[(l * 9 + c16) * 256 + b] = ah4[r];
            }
        }
    }
}

// ======== extend: depth-3 prefetch; emits per-fragment frame + endpoint ========
__global__ __launch_bounds__(64) void extend_kernel(KParams P) {
    int frag = blockIdx.x >> 2;
    int bb   = ((blockIdx.x & 3) << 6) + threadIdx.x;

    float3 A  = make_float3(-0.70710678118654752f, 1.22474487139158905f, 0.f);
    float3 Bv = make_float3(-1.41421356237309505f, 0.f, 0.f);
    float3 C  = make_float3(0.f, 0.f, 0.f);

    float ct0[9], ct1[9], ct2[9], ct3[9];
    #pragma unroll
    for (int m = 0; m < 9; ++m) {
        ct0[m] = P.srf_t[((frag * 32 + 0) * 9 + m) * 256 + bb];
        ct1[m] = P.srf_t[((frag * 32 + 1) * 9 + m) * 256 + bb];
        ct2[m] = P.srf_t[((frag * 32 + 2) * 9 + m) * 256 + bb];
    }
    for (int ll = 0; ll < 32; ++ll) {
        if (ll < 29) {
            #pragma unroll
            for (int m = 0; m < 9; ++m)
                ct3[m] = P.srf_t[((frag * 32 + ll + 3) * 9 + m) * 256 + bb];
        } else {
            #pragma unroll
            for (int m = 0; m < 9; ++m) ct3[m] = 0.f;
        }
        #pragma unroll
        for (int s3 = 0; s3 < 3; ++s3) {
            float3 bc, nn, m3;
            nerf_frame(A, Bv, C, bc, nn, m3);
            float3 d = nerf_place(C, bc, m3, nn,
                                  ct0[3 * s3 + 0], ct0[3 * s3 + 1], ct0[3 * s3 + 2]);
            int row = frag * 96 + ll * 3 + s3;
            P.fragbuf[(row * 3 + 0) * 256 + bb] = d.x;
            P.fragbuf[(row * 3 + 1) * 256 + bb] = d.y;
            P.fragbuf[(row * 3 + 2) * 256 + bb] = d.z;
            A = Bv; Bv = C; C = d;
        }
        #pragma unroll
        for (int m = 0; m < 9; ++m) { ct0[m] = ct1[m]; ct1[m] = ct2[m]; ct2[m] = ct3[m]; }
    }
    float3 bc, nn, m3;
    nerf_frame(A, Bv, C, bc, nn, m3);
    P.FPbuf[(frag * 12 + 0)  * 256 + bb] = bc.x;
    P.FPbuf[(frag * 12 + 1)  * 256 + bb] = bc.y;
    P.FPbuf[(frag * 12 + 2)  * 256 + bb] = bc.z;
    P.FPbuf[(frag * 12 + 3)  * 256 + bb] = m3.x;
    P.FPbuf[(frag * 12 + 4)  * 256 + bb] = m3.y;
    P.FPbuf[(frag * 12 + 5)  * 256 + bb] = m3.z;
    P.FPbuf[(frag * 12 + 6)  * 256 + bb] = nn.x;
    P.FPbuf[(frag * 12 + 7)  * 256 + bb] = nn.y;
    P.FPbuf[(frag * 12 + 8)  * 256 + bb] = nn.z;
    P.FPbuf[(frag * 12 + 9)  * 256 + bb] = C.x;
    P.FPbuf[(frag * 12 + 10) * 256 + bb] = C.y;
    P.FPbuf[(frag * 12 + 11) * 256 + bb] = C.z;
}

// ======== carry: rotation-composition over fragment constants (LDS-staged) ====
__global__ __launch_bounds__(256) void carry_kernel(KParams P) {
    __shared__ float S[384][16];
    const int tid  = threadIdx.x;
    const int base = blockIdx.x * 16;
    for (int i = tid; i < 384 * 16; i += 256) {
        int row = i >> 4, col = i & 15;
        S[row][col] = P.FPbuf[row * 256 + base + col];
    }
    __syncthreads();
    if (tid < 16) {
        int bb = base + tid;
        float3 ob = make_float3(1.f, 0.f, 0.f);
        float3 om = make_float3(0.f, 1.f, 0.f);
        float3 on = make_float3(0.f, 0.f, 1.f);
        float3 c  = make_float3(0.f, 0.f, 0.f);
        for (int f = 0; f < 32; ++f) {
            int fb = (f * 256 + bb) * 3;
            P.frames[fb + 0] = make_float4(ob.x, ob.y, ob.z, om.x);
            P.frames[fb + 1] = make_float4(om.y, om.z, on.x, on.y);
            P.frames[fb + 2] = make_float4(on.z, c.x, c.y, c.z);

            int r0 = f * 12;
            float3 Fb = make_float3(S[r0+0][tid], S[r0+1][tid], S[r0+2][tid]);
            float3 Fm = make_float3(S[r0+3][tid], S[r0+4][tid], S[r0+5][tid]);
            float3 Fn = make_float3(S[r0+6][tid], S[r0+7][tid], S[r0+8][tid]);
            float3 p  = make_float3(S[r0+9][tid], S[r0+10][tid], S[r0+11][tid]);

            float3 nb = make_float3(
                fmaf(ob.x,Fb.x, fmaf(om.x,Fb.y, on.x*Fb.z)),
                fmaf(ob.y,Fb.x, fmaf(om.y,Fb.y, on.y*Fb.z)),
                fmaf(ob.z,Fb.x, fmaf(om.z,Fb.y, on.z*Fb.z)));
            float3 nm = make_float3(
                fmaf(ob.x,Fm.x, fmaf(om.x,Fm.y, on.x*Fm.z)),
                fmaf(ob.y,Fm.x, fmaf(om.y,Fm.y, on.y*Fm.z)),
                fmaf(ob.z,Fm.x, fmaf(om.z,Fm.y, on.z*Fm.z)));
            float3 nn2 = make_float3(
                fmaf(ob.x,Fn.x, fmaf(om.x,Fn.y, on.x*Fn.z)),
                fmaf(ob.y,Fn.x, fmaf(om.y,Fn.y, on.y*Fn.z)),
                fmaf(ob.z,Fn.x, fmaf(om.z,Fn.y, on.z*Fn.z)));
            float3 nc = make_float3(
                fmaf(ob.x,p.x, fmaf(om.x,p.y, fmaf(on.x,p.z, c.x))),
                fmaf(ob.y,p.x, fmaf(om.y,p.y, fmaf(on.y,p.z, c.y))),
                fmaf(ob.z,p.x, fmaf(om.z,p.y, fmaf(on.z,p.z, c.z))));
            ob = nb; om = nm; on = nn2; c = nc;
        }
    }
}

// ======== apply: 4 rows/block; LDS-staged coalesced output ========
__global__ __launch_bounds__(256) void apply_kernel(KParams P) {
    __shared__ float sm[768];
    const int bb = threadIdx.x;
    #pragma unroll 1
    for (int i = 0; i < 4; ++i) {
        const int row  = blockIdx.x * 4 + i;
        const int frag = row / 96;

        float fx = P.fragbuf[(row * 3 + 0) * 256 + bb];
        float fy = P.fragbuf[(row * 3 + 1) * 256 + bb];
        float fz = P.fragbuf[(row * 3 + 2) * 256 + bb];

        int fb = (frag * 256 + bb) * 3;
        float4 f0 = P.frames[fb + 0];
        float4 f1 = P.frames[fb + 1];
        float4 f2 = P.frames[fb + 2];

        float ox = f2.y + f0.x * fx + f0.w * fy + f1.z * fz;
        float oy = f2.z + f0.y * fx + f1.x * fy + f1.w * fz;
        float oz = f2.w + f0.z * fx + f1.y * fy + f2.x * fz;

        __syncthreads();   // prior iteration's sm reads complete
        sm[bb * 3 + 0] = ox;
        sm[bb * 3 + 1] = oy;
        sm[bb * 3 + 2] = oz;
        __syncthreads();

        int base = row * 768;
        P.out[base + bb]       = sm[bb];
        P.out[base + 256 + bb] = sm[256 + bb];
        P.out[base + 512 + bb] = sm[512 + bb];
    }
}

// ======== host launch: 5-dispatch path (coop fusion measured 2.3x worse:
// grid.sync ~90us each on 8-XCD MI355X — r10) ========
extern "C" void kernel_launch(void* const* d_in, const int* in_sizes, int n_in,
                              void* d_out, int out_size, void* d_ws, size_t ws_size,
                              hipStream_t stream) {
    float* ws      = (float*)d_ws;
    float* kmerT   = ws;                       // 10648*64 = 681472
    float* seqT    = kmerT + 681472;           // 1280
    float* srf_t   = seqT + 1280;              // 2359296
    float* fragbuf = srf_t + 2359296;          // 2359296
    float* frames  = fragbuf + 2359296;        // 98304 (float4-accessed)
    float* FPbuf   = frames + 98304;           // 98304

    // split weight tables alias fragbuf (tables writes -> mlp reads -> extend
    // overwrites; strictly ordered by kernel boundaries)
    unsigned short* WeTH  = (unsigned short*)fragbuf;
    unsigned short* WeTL  = WeTH + 4096;
    unsigned short* W0pTH = WeTL + 4096;
    unsigned short* W0pTL = W0pTH + 2048;
    unsigned short* W1TH  = W0pTL + 2048;
    unsigned short* W1TL  = W1TH + 1024;

    KParams P;
    P.seq  = (const int*)d_in[0];
    P.kmer = (const int*)d_in[1];
    P.pssm = (const float*)d_in[2];
    P.se   = (const float*)d_in[4];
    P.emb  = (const float*)d_in[5];
    P.W0   = (const float*)d_in[6];
    P.b0   = (const float*)d_in[7];
    P.We   = (const float*)d_in[8];
    P.be   = (const float*)d_in[9];
    P.W1   = (const float*)d_in[10];
    P.b1   = (const float*)d_in[11];
    P.kmerT = kmerT; P.seqT = seqT; P.srf_t = srf_t; P.fragbuf = fragbuf;
    P.frames = (float4*)frames; P.FPbuf = FPbuf; P.out = (float*)d_out;
    P.WeTH = WeTH; P.WeTL = WeTL; P.W0pTH = W0pTH; P.W0pTL = W0pTL;
    P.W1TH = W1TH; P.W1TL = W1TL;

    hipLaunchKernelGGL(tables_kernel, dim3(173),  dim3(256), 0, stream, P);
    hipLaunchKernelGGL(mlp_kernel,    dim3(4096), dim3(256), 0, stream, P);
    hipLaunchKernelGGL(extend_kernel, dim3(128),  dim3(64),  0, stream, P);
    hipLaunchKernelGGL(carry_kernel,  dim3(16),   dim3(256), 0, stream, P);
    hipLaunchKernelGGL(apply_kernel,  dim3(768),  dim3(256), 0, stream, P);
}

// Round 7
// 175.805 us; speedup vs baseline: 1.2969x; 1.0225x over previous
//
#include <hip/hip_runtime.h>
#include <math.h>

typedef short bf16x8 __attribute__((ext_vector_type(8)));
typedef float f32x4  __attribute__((ext_vector_type(4)));

// round-to-nearest-even float -> bf16 bits
__device__ __forceinline__ unsigned short f2bf(float x) {
    unsigned int u = __float_as_uint(x);
    return (unsigned short)((u + 0x7FFFu + ((u >> 16) & 1u)) >> 16);
}
__device__ __forceinline__ float bf2f(unsigned short h) {
    return __uint_as_float(((unsigned int)h) << 16);
}
// RNE split (precompute path)
__device__ __forceinline__ void split2(float x, unsigned short& h, unsigned short& l) {
    h = f2bf(x);
    l = f2bf(x - bf2f(h));
}
// truncation split (hot path): hi = trunc(x), lo = RNE(x-hi); combined rel err ~2^-17
__device__ __forceinline__ void split2t(float x, unsigned short& h, unsigned short& l) {
    unsigned int u = __float_as_uint(x);
    h = (unsigned short)(u >> 16);
    float r = x - __uint_as_float(u & 0xFFFF0000u);
    l = f2bf(r);
}

// XOR-swizzled H index (shorts): stride 64 shorts (128 B rows).
// Bank analysis (32 banks x 4B): row stride = 32 dwords == 0 mod 32, so bank is
// set by the 16B chunk only; chunk' = chunk ^ (row&7) spreads 16 consecutive
// rows over 8 chunks = 32 banks -> 2-way on b128 reads (free, m136).
// Measured 688K conflicts vs 3.05M for the old stride-72 pad (r13/r14).
__device__ __forceinline__ int hsw(int row, int col) {
    return (row << 6) + ((((col >> 3) ^ (row & 7)) << 3) | (col & 7));
}

__device__ __forceinline__ float inv_norm3(float x, float y, float z) {
    float d = fmaf(x, x, fmaf(y, y, z * z));
    return rsqrtf(fmaxf(d, 1e-24f));
}
__device__ __forceinline__ float3 f3sub(float3 a, float3 b) {
    return make_float3(a.x - b.x, a.y - b.y, a.z - b.z);
}
__device__ __forceinline__ float3 f3cross(float3 a, float3 b) {
    return make_float3(a.y * b.z - a.z * b.y,
                       a.z * b.x - a.x * b.z,
                       a.x * b.y - a.y * b.x);
}
// NeRF frame, parallel normalizations (n from unnormalized w: same direction)
__device__ __forceinline__ void nerf_frame(const float3& A, const float3& Bv,
                                           const float3& C, float3& bc,
                                           float3& n, float3& m3) {
    float3 w  = f3sub(C, Bv);
    float3 v  = f3sub(Bv, A);
    float3 cr = f3cross(v, w);
    float iw = inv_norm3(w.x, w.y, w.z);
    float ic = inv_norm3(cr.x, cr.y, cr.z);
    bc = make_float3(w.x * iw, w.y * iw, w.z * iw);
    n  = make_float3(cr.x * ic, cr.y * ic, cr.z * ic);
    m3 = f3cross(n, bc);
}
__device__ __forceinline__ float3 nerf_place(const float3& C, const float3& bc,
                                             const float3& m3, const float3& n,
                                             float tx, float ty, float tz) {
    return make_float3(
        fmaf(m3.x, ty, fmaf(bc.x, tx, fmaf(n.x, tz, C.x))),
        fmaf(m3.y, ty, fmaf(bc.y, tx, fmaf(n.y, tz, C.y))),
        fmaf(m3.z, ty, fmaf(bc.z, tx, fmaf(n.z, tz, C.z))));
}

struct KParams {
    const int* seq; const int* kmer; const float* pssm;
    const float* se; const float* emb;
    const float* W0; const float* b0; const float* We; const float* be;
    const float* W1; const float* b1;
    float* kmerT; float* seqT; float* srf_t; float* fragbuf;
    float4* frames; float* FPbuf; float* out;
    unsigned short *WeTH, *WeTL, *W0pTH, *W0pTL, *W1TH, *W1TL;
};

// ======== tables: kmerT via split-bf16 MFMA (vector loads), seqT, weight tables
__global__ __launch_bounds__(256) void tables_kernel(KParams P) {
    const int tid = threadIdx.x;
    const int vb  = blockIdx.x;
    if (vb < 167) {
        const int lane = tid & 63;
        const int wv   = __builtin_amdgcn_readfirstlane(tid >> 6);
        const int q    = lane >> 4;
        const int c16  = lane & 15;
        const int r0   = vb * 64;
        const int n    = wv * 16 + c16;

        bf16x8 BH[8], BL[8];
        #pragma unroll
        for (int kt8 = 0; kt8 < 8; ++kt8)
            #pragma unroll
            for (int j = 0; j < 8; ++j) {
                float w = P.W0[(16 + kt8 * 32 + q * 8 + j) * 64 + n];
                unsigned short h, l; split2t(w, h, l);
                BH[kt8][j] = (short)h; BL[kt8][j] = (short)l;
            }
        f32x4 acc[4];
        #pragma unroll
        for (int t = 0; t < 4; ++t) acc[t] = (f32x4){0.f, 0.f, 0.f, 0.f};
        #pragma unroll
        for (int kt8 = 0; kt8 < 8; ++kt8) {
            #pragma unroll
            for (int t = 0; t < 4; ++t) {
                int rr = r0 + t * 16 + c16;
                if (rr > 10647) rr = 10647;
                const float* ap = P.emb + rr * 256 + kt8 * 32 + q * 8;
                float4 a0 = *(const float4*)ap;
                float4 a1 = *(const float4*)(ap + 4);
                bf16x8 ah, al;
                unsigned short h, l;
                split2t(a0.x, h, l); ah[0] = (short)h; al[0] = (short)l;
                split2t(a0.y, h, l); ah[1] = (short)h; al[1] = (short)l;
                split2t(a0.z, h, l); ah[2] = (short)h; al[2] = (short)l;
                split2t(a0.w, h, l); ah[3] = (short)h; al[3] = (short)l;
                split2t(a1.x, h, l); ah[4] = (short)h; al[4] = (short)l;
                split2t(a1.y, h, l); ah[5] = (short)h; al[5] = (short)l;
                split2t(a1.z, h, l); ah[6] = (short)h; al[6] = (short)l;
                split2t(a1.w, h, l); ah[7] = (short)h; al[7] = (short)l;
                acc[t] = __builtin_amdgcn_mfma_f32_16x16x32_bf16(ah, BH[kt8], acc[t], 0, 0, 0);
                acc[t] = __builtin_amdgcn_mfma_f32_16x16x32_bf16(al, BH[kt8], acc[t], 0, 0, 0);
                acc[t] = __builtin_amdgcn_mfma_f32_16x16x32_bf16(ah, BL[kt8], acc[t], 0, 0, 0);
            }
        }
        #pragma unroll
        for (int t = 0; t < 4; ++t)
            #pragma unroll
            for (int r = 0; r < 4; ++r) {
                int row = r0 + t * 16 + q * 4 + r;
                if (row < 10648) P.kmerT[row * 64 + n] = acc[t][r];
            }
    } else if (vb < 172) {
        // seqT[r][j] = seq_embed[r]@W0[0:16] + b0[j] + 0.5*sum_c W0p[c][j]
        int e = (vb - 167) * 256 + tid;
        int r = e >> 6, j = e & 63;
        float acc = P.b0[j];
        #pragma unroll
        for (int k = 0; k < 16; ++k)
            acc = fmaf(P.se[r * 16 + k], P.W0[k * 64 + j], acc);
        float cs = 0.f;
        #pragma unroll
        for (int c = 0; c < 21; ++c) cs += P.W0[(272 + c) * 64 + j];
        P.seqT[r * 64 + j] = acc + 0.5f * cs;
    } else {
        #pragma unroll
        for (int i = 0; i < 16; ++i) {
            int e = i * 256 + tid;
            int k = e >> 6, n = e & 63;
            unsigned short h, l; split2(P.We[k * 64 + n], h, l);
            P.WeTH[n * 64 + k] = h; P.WeTL[n * 64 + k] = l;
        }
        #pragma unroll
        for (int i = 0; i < 8; ++i) {
            int e = i * 256 + tid;
            int k = e >> 6, n = e & 63;
            float w = (k < 21) ? P.W0[(272 + k) * 64 + n] : 0.f;
            unsigned short h, l; split2(w, h, l);
            P.W0pTH[n * 32 + k] = h; P.W0pTL[n * 32 + k] = l;
        }
        #pragma unroll
        for (int i = 0; i < 4; ++i) {
            int e = i * 256 + tid;
            int k = e >> 4, c = e & 15;
            float w = (c < 9) ? P.W1[k * 9 + c] : 0.f;
            unsigned short h, l; split2(w, h, l);
            P.W1TH[c * 64 + k] = h; P.W1TL[c * 64 + k] = l;
        }
    }
}

// ======== split-bf16 MFMA MLP — r19: r14 revert + packed-index bpermute ======
// Post-mortems r13-r18: conflicts off critical path (r14/r16); occupancy knobs
// inert (r13) and occupancy 70% even regresses via prologue duplication (r17);
// M-split = regalloc trap (r15); staging removal = VMEM trap (r16); halving
// DS ops rebalances onto VALU at zero net gain (r18). The kernel is
// phase-chain-limited with all pipes <=60%; r14's exact structure is the
// measured floor (~47.5us). r19 = r14 verbatim, plus the one residual free
// win from r18: seq|kmer<<5 packed into one dword -> 16 ds_bpermute instead
// of 32 (unpack = 1 AND + 1 SHR per pair; identical indices -> identical
// gathers -> bit-identical output).
__global__ __launch_bounds__(256, 4) void mlp_kernel(KParams P) {
    __shared__ __align__(16) unsigned char SMEM[32768];
    unsigned short* Hah = (unsigned short*)(SMEM);            // swizzled, 8192 B
    unsigned short* Hal = (unsigned short*)(SMEM + 8192);
    unsigned short* Hbh = (unsigned short*)(SMEM + 16384);
    unsigned short* Hbl = (unsigned short*)(SMEM + 24576);
    unsigned short (*Ph)[40] = (unsigned short (*)[40])(SMEM + 16384);  // overlay on Hb
    unsigned short (*Pl)[40] = (unsigned short (*)[40])(SMEM + 16384 + 5120);

    const int tid  = threadIdx.x;
    const int lane = tid & 63;
    const int wv   = __builtin_amdgcn_readfirstlane(tid >> 6);
    const int q    = lane >> 4;
    const int c16  = lane & 15;
    const int m0   = blockIdx.x * 64;
    const int n    = wv * 16 + c16;

    // ---- indices: one coalesced load per lane, seq|kmer packed in one dword
    //      (seq<32 -> 5 bits, kmer<10648 -> 14 bits); 16 bpermutes (was 32);
    //      gathers issue immediately (no barrier dependency) ----
    const int mypack = P.seq[m0 + lane] | (P.kmer[m0 + lane] << 5);
    float g[4][4];
    #pragma unroll
    for (int t = 0; t < 4; ++t)
        #pragma unroll
        for (int r = 0; r < 4; ++r) {
            int src = (t * 16 + q * 4 + r) << 2;
            int v   = __builtin_amdgcn_ds_bpermute(src, mypack);
            int s   = v & 31;
            int km  = v >> 5;
            g[t][r] = P.seqT[s * 64 + n] + P.kmerT[km * 64 + n];
        }

    // ---- stage centered pssm (trunc-split) into LDS overlay ----
    for (int i = tid; i < 64 * 21; i += 256) {
        float v = P.pssm[m0 * 21 + i] - 0.5f;
        unsigned short h, l; split2t(v, h, l);
        Ph[i / 21][i % 21] = h;
        Pl[i / 21][i % 21] = l;
    }
    for (int i = tid; i < 64 * 11; i += 256) {
        Ph[i / 11][21 + (i % 11)] = 0;
        Pl[i / 11][21 + (i % 11)] = 0;
    }

    // ---- weight fragments + biases (L1/L2-hot 16B loads) ----
    bf16x8 WeH[2], WeL[2], W1H[2], W1L[2], W0H, W0L;
    #pragma unroll
    for (int kk = 0; kk < 2; ++kk) {
        WeH[kk] = *(const bf16x8*)(P.WeTH + n * 64 + kk * 32 + q * 8);
        WeL[kk] = *(const bf16x8*)(P.WeTL + n * 64 + kk * 32 + q * 8);
        W1H[kk] = *(const bf16x8*)(P.W1TH + c16 * 64 + kk * 32 + q * 8);
        W1L[kk] = *(const bf16x8*)(P.W1TL + c16 * 64 + kk * 32 + q * 8);
    }
    W0H = *(const bf16x8*)(P.W0pTH + n * 32 + q * 8);
    W0L = *(const bf16x8*)(P.W0pTL + n * 32 + q * 8);
    const float be_n = P.be[n];
    const float b1h  = (c16 < 9) ? P.b1[c16] : 0.f;
    __syncthreads();

    // ---- layer 0: zero-init MFMA, then add gathers late ----
    f32x4 acc[4];
    #pragma unroll
    for (int t = 0; t < 4; ++t) acc[t] = (f32x4){0.f, 0.f, 0.f, 0.f};
    #pragma unroll
    for (int t = 0; t < 4; ++t) {
        bf16x8 ah = *(const bf16x8*)&Ph[t * 16 + c16][q * 8];
        bf16x8 al = *(const bf16x8*)&Pl[t * 16 + c16][q * 8];
        acc[t] = __builtin_amdgcn_mfma_f32_16x16x32_bf16(ah, W0H, acc[t], 0, 0, 0);
        acc[t] = __builtin_amdgcn_mfma_f32_16x16x32_bf16(al, W0H, acc[t], 0, 0, 0);
        acc[t] = __builtin_amdgcn_mfma_f32_16x16x32_bf16(ah, W0L, acc[t], 0, 0, 0);
    }
    #pragma unroll
    for (int t = 0; t < 4; ++t)
        #pragma unroll
        for (int r = 0; r < 4; ++r) {
            unsigned short h, l; split2t(acc[t][r] + g[t][r], h, l);
            Hah[hsw(t * 16 + q * 4 + r, n)] = h;
            Hal[hsw(t * 16 + q * 4 + r, n)] = l;
        }
    __syncthreads();   // h0 ready; pssm reads done -> Hb overlay reusable

    // ---- layer 1: Ha -> Hb (relu) ----
    {
        f32x4 a1[4];
        #pragma unroll
        for (int t = 0; t < 4; ++t) {
            a1[t] = (f32x4){be_n, be_n, be_n, be_n};
            #pragma unroll
            for (int kk = 0; kk < 2; ++kk) {
                bf16x8 ah = *(const bf16x8*)&Hah[hsw(t * 16 + c16, kk * 32 + q * 8)];
                bf16x8 al = *(const bf16x8*)&Hal[hsw(t * 16 + c16, kk * 32 + q * 8)];
                a1[t] = __builtin_amdgcn_mfma_f32_16x16x32_bf16(ah, WeH[kk], a1[t], 0, 0, 0);
                a1[t] = __builtin_amdgcn_mfma_f32_16x16x32_bf16(al, WeH[kk], a1[t], 0, 0, 0);
                a1[t] = __builtin_amdgcn_mfma_f32_16x16x32_bf16(ah, WeL[kk], a1[t], 0, 0, 0);
            }
        }
        #pragma unroll
        for (int t = 0; t < 4; ++t)
            #pragma unroll
            for (int r = 0; r < 4; ++r) {
                unsigned short h, l; split2t(fmaxf(a1[t][r], 0.f), h, l);
                Hbh[hsw(t * 16 + q * 4 + r, n)] = h;
                Hbl[hsw(t * 16 + q * 4 + r, n)] = l;
            }
        __syncthreads();
    }
    // ---- layer 2: Hb -> Ha (relu) ----
    {
        f32x4 a2[4];
        #pragma unroll
        for (int t = 0; t < 4; ++t) {
            a2[t] = (f32x4){be_n, be_n, be_n, be_n};
            #pragma unroll
            for (int kk = 0; kk < 2; ++kk) {
                bf16x8 ah = *(const bf16x8*)&Hbh[hsw(t * 16 + c16, kk * 32 + q * 8)];
                bf16x8 al = *(const bf16x8*)&Hbl[hsw(t * 16 + c16, kk * 32 + q * 8)];
                a2[t] = __builtin_amdgcn_mfma_f32_16x16x32_bf16(ah, WeH[kk], a2[t], 0, 0, 0);
                a2[t] = __builtin_amdgcn_mfma_f32_16x16x32_bf16(al, WeH[kk], a2[t], 0, 0, 0);
                a2[t] = __builtin_amdgcn_mfma_f32_16x16x32_bf16(ah, WeL[kk], a2[t], 0, 0, 0);
            }
        }
        #pragma unroll
        for (int t = 0; t < 4; ++t)
            #pragma unroll
            for (int r = 0; r < 4; ++r) {
                unsigned short h, l; split2t(fmaxf(a2[t][r], 0.f), h, l);
                Hah[hsw(t * 16 + q * 4 + r, n)] = h;
                Hal[hsw(t * 16 + q * 4 + r, n)] = l;
            }
        __syncthreads();
    }
    // ---- head: wave wv does M-tile wv ----
    {
        f32x4 ah4 = (f32x4){b1h, b1h, b1h, b1h};
        #pragma unroll
        for (int kk = 0; kk < 2; ++kk) {
            bf16x8 ah = *(const bf16x8*)&Hah[hsw(wv * 16 + c16, kk * 32 + q * 8)];
            bf16x8 al = *(const bf16x8*)&Hal[hsw(wv * 16 + c16, kk * 32 + q * 8)];
            ah4 = __builtin_amdgcn_mfma_f32_16x16x32_bf16(ah, W1H[kk], ah4, 0, 0, 0);
            ah4 = __builtin_amdgcn_mfma_f32_16x16x32_bf16(al, W1H[kk], ah4, 0, 0, 0);
            ah4 = __builtin_amdgcn_mfma_f32_16x16x32_bf16(ah, W1L[kk], ah4, 0, 0, 0);
        }
        if (c16 < 9) {
            #pragma unroll
            for (int r = 0; r < 4; ++r) {
                int pos = m0 + wv * 16 + q * 4 + r;
                int l = pos >> 8, b = pos & 255;
                P.srf_t[(l * 9 + c16) * 256 + b] = ah4[r];
            }
        }
    }
}

// ======== extend: depth-3 prefetch; emits per-fragment frame + endpoint ========
__global__ __launch_bounds__(64) void extend_kernel(KParams P) {
    int frag = blockIdx.x >> 2;
    int bb   = ((blockIdx.x & 3) << 6) + threadIdx.x;

    float3 A  = make_float3(-0.70710678118654752f, 1.22474487139158905f, 0.f);
    float3 Bv = make_float3(-1.41421356237309505f, 0.f, 0.f);
    float3 C  = make_float3(0.f, 0.f, 0.f);

    float ct0[9], ct1[9], ct2[9], ct3[9];
    #pragma unroll
    for (int m = 0; m < 9; ++m) {
        ct0[m] = P.srf_t[((frag * 32 + 0) * 9 + m) * 256 + bb];
        ct1[m] = P.srf_t[((frag * 32 + 1) * 9 + m) * 256 + bb];
        ct2[m] = P.srf_t[((frag * 32 + 2) * 9 + m) * 256 + bb];
    }
    for (int ll = 0; ll < 32; ++ll) {
        if (ll < 29) {
            #pragma unroll
            for (int m = 0; m < 9; ++m)
                ct3[m] = P.srf_t[((frag * 32 + ll + 3) * 9 + m) * 256 + bb];
        } else {
            #pragma unroll
            for (int m = 0; m < 9; ++m) ct3[m] = 0.f;
        }
        #pragma unroll
        for (int s3 = 0; s3 < 3; ++s3) {
            float3 bc, nn, m3;
            nerf_frame(A, Bv, C, bc, nn, m3);
            float3 d = nerf_place(C, bc, m3, nn,
                                  ct0[3 * s3 + 0], ct0[3 * s3 + 1], ct0[3 * s3 + 2]);
            int row = frag * 96 + ll * 3 + s3;
            P.fragbuf[(row * 3 + 0) * 256 + bb] = d.x;
            P.fragbuf[(row * 3 + 1) * 256 + bb] = d.y;
            P.fragbuf[(row * 3 + 2) * 256 + bb] = d.z;
            A = Bv; Bv = C; C = d;
        }
        #pragma unroll
        for (int m = 0; m < 9; ++m) { ct0[m] = ct1[m]; ct1[m] = ct2[m]; ct2[m] = ct3[m]; }
    }
    float3 bc, nn, m3;
    nerf_frame(A, Bv, C, bc, nn, m3);
    P.FPbuf[(frag * 12 + 0)  * 256 + bb] = bc.x;
    P.FPbuf[(frag * 12 + 1)  * 256 + bb] = bc.y;
    P.FPbuf[(frag * 12 + 2)  * 256 + bb] = bc.z;
    P.FPbuf[(frag * 12 + 3)  * 256 + bb] = m3.x;
    P.FPbuf[(frag * 12 + 4)  * 256 + bb] = m3.y;
    P.FPbuf[(frag * 12 + 5)  * 256 + bb] = m3.z;
    P.FPbuf[(frag * 12 + 6)  * 256 + bb] = nn.x;
    P.FPbuf[(frag * 12 + 7)  * 256 + bb] = nn.y;
    P.FPbuf[(frag * 12 + 8)  * 256 + bb] = nn.z;
    P.FPbuf[(frag * 12 + 9)  * 256 + bb] = C.x;
    P.FPbuf[(frag * 12 + 10) * 256 + bb] = C.y;
    P.FPbuf[(frag * 12 + 11) * 256 + bb] = C.z;
}

// ======== carry: rotation-composition over fragment constants (LDS-staged) ====
__global__ __launch_bounds__(256) void carry_kernel(KParams P) {
    __shared__ float S[384][16];
    const int tid  = threadIdx.x;
    const int base = blockIdx.x * 16;
    for (int i = tid; i < 384 * 16; i += 256) {
        int row = i >> 4, col = i & 15;
        S[row][col] = P.FPbuf[row * 256 + base + col];
    }
    __syncthreads();
    if (tid < 16) {
        int bb = base + tid;
        float3 ob = make_float3(1.f, 0.f, 0.f);
        float3 om = make_float3(0.f, 1.f, 0.f);
        float3 on = make_float3(0.f, 0.f, 1.f);
        float3 c  = make_float3(0.f, 0.f, 0.f);
        for (int f = 0; f < 32; ++f) {
            int fb = (f * 256 + bb) * 3;
            P.frames[fb + 0] = make_float4(ob.x, ob.y, ob.z, om.x);
            P.frames[fb + 1] = make_float4(om.y, om.z, on.x, on.y);
            P.frames[fb + 2] = make_float4(on.z, c.x, c.y, c.z);

            int r0 = f * 12;
            float3 Fb = make_float3(S[r0+0][tid], S[r0+1][tid], S[r0+2][tid]);
            float3 Fm = make_float3(S[r0+3][tid], S[r0+4][tid], S[r0+5][tid]);
            float3 Fn = make_float3(S[r0+6][tid], S[r0+7][tid], S[r0+8][tid]);
            float3 p  = make_float3(S[r0+9][tid], S[r0+10][tid], S[r0+11][tid]);

            float3 nb = make_float3(
                fmaf(ob.x,Fb.x, fmaf(om.x,Fb.y, on.x*Fb.z)),
                fmaf(ob.y,Fb.x, fmaf(om.y,Fb.y, on.y*Fb.z)),
                fmaf(ob.z,Fb.x, fmaf(om.z,Fb.y, on.z*Fb.z)));
            float3 nm = make_float3(
                fmaf(ob.x,Fm.x, fmaf(om.x,Fm.y, on.x*Fm.z)),
                fmaf(ob.y,Fm.x, fmaf(om.y,Fm.y, on.y*Fm.z)),
                fmaf(ob.z,Fm.x, fmaf(om.z,Fm.y, on.z*Fm.z)));
            float3 nn2 = make_float3(
                fmaf(ob.x,Fn.x, fmaf(om.x,Fn.y, on.x*Fn.z)),
                fmaf(ob.y,Fn.x, fmaf(om.y,Fn.y, on.y*Fn.z)),
                fmaf(ob.z,Fn.x, fmaf(om.z,Fn.y, on.z*Fn.z)));
            float3 nc = make_float3(
                fmaf(ob.x,p.x, fmaf(om.x,p.y, fmaf(on.x,p.z, c.x))),
                fmaf(ob.y,p.x, fmaf(om.y,p.y, fmaf(on.y,p.z, c.y))),
                fmaf(ob.z,p.x, fmaf(om.z,p.y, fmaf(on.z,p.z, c.z))));
            ob = nb; om = nm; on = nn2; c = nc;
        }
    }
}

// ======== apply: 4 rows/block; LDS-staged coalesced output ========
__global__ __launch_bounds__(256) void apply_kernel(KParams P) {
    __shared__ float sm[768];
    const int bb = threadIdx.x;
    #pragma unroll 1
    for (int i = 0; i < 4; ++i) {
        const int row  = blockIdx.x * 4 + i;
        const int frag = row / 96;

        float fx = P.fragbuf[(row * 3 + 0) * 256 + bb];
        float fy = P.fragbuf[(row * 3 + 1) * 256 + bb];
        float fz = P.fragbuf[(row * 3 + 2) * 256 + bb];

        int fb = (frag * 256 + bb) * 3;
        float4 f0 = P.frames[fb + 0];
        float4 f1 = P.frames[fb + 1];
        float4 f2 = P.frames[fb + 2];

        float ox = f2.y + f0.x * fx + f0.w * fy + f1.z * fz;
        float oy = f2.z + f0.y * fx + f1.x * fy + f1.w * fz;
        float oz = f2.w + f0.z * fx + f1.y * fy + f2.x * fz;

        __syncthreads();   // prior iteration's sm reads complete
        sm[bb * 3 + 0] = ox;
        sm[bb * 3 + 1] = oy;
        sm[bb * 3 + 2] = oz;
        __syncthreads();

        int base = row * 768;
        P.out[base + bb]       = sm[bb];
        P.out[base + 256 + bb] = sm[256 + bb];
        P.out[base + 512 + bb] = sm[512 + bb];
    }
}

// ======== host launch: 5-dispatch path (coop fusion measured 2.3x worse:
// grid.sync ~90us each on 8-XCD MI355X — r10) ========
extern "C" void kernel_launch(void* const* d_in, const int* in_sizes, int n_in,
                              void* d_out, int out_size, void* d_ws, size_t ws_size,
                              hipStream_t stream) {
    float* ws      = (float*)d_ws;
    float* kmerT   = ws;                       // 10648*64 = 681472
    float* seqT    = kmerT + 681472;           // 1280
    float* srf_t   = seqT + 1280;              // 2359296
    float* fragbuf = srf_t + 2359296;          // 2359296
    float* frames  = fragbuf + 2359296;        // 98304 (float4-accessed)
    float* FPbuf   = frames + 98304;           // 98304

    // split weight tables alias fragbuf (tables writes -> mlp reads -> extend
    // overwrites; strictly ordered by kernel boundaries)
    unsigned short* WeTH  = (unsigned short*)fragbuf;
    unsigned short* WeTL  = WeTH + 4096;
    unsigned short* W0pTH = WeTL + 4096;
    unsigned short* W0pTL = W0pTH + 2048;
    unsigned short* W1TH  = W0pTL + 2048;
    unsigned short* W1TL  = W1TH + 1024;

    KParams P;
    P.seq  = (const int*)d_in[0];
    P.kmer = (const int*)d_in[1];
    P.pssm = (const float*)d_in[2];
    P.se   = (const float*)d_in[4];
    P.emb  = (const float*)d_in[5];
    P.W0   = (const float*)d_in[6];
    P.b0   = (const float*)d_in[7];
    P.We   = (const float*)d_in[8];
    P.be   = (const float*)d_in[9];
    P.W1   = (const float*)d_in[10];
    P.b1   = (const float*)d_in[11];
    P.kmerT = kmerT; P.seqT = seqT; P.srf_t = srf_t; P.fragbuf = fragbuf;
    P.frames = (float4*)frames; P.FPbuf = FPbuf; P.out = (float*)d_out;
    P.WeTH = WeTH; P.WeTL = WeTL; P.W0pTH = W0pTH; P.W0pTL = W0pTL;
    P.W1TH = W1TH; P.W1TL = W1TL;

    hipLaunchKernelGGL(tables_kernel, dim3(173),  dim3(256), 0, stream, P);
    hipLaunchKernelGGL(mlp_kernel,    dim3(4096), dim3(256), 0, stream, P);
    hipLaunchKernelGGL(extend_kernel, dim3(128),  dim3(64),  0, stream, P);
    hipLaunchKernelGGL(carry_kernel,  dim3(16),   dim3(256), 0, stream, P);
    hipLaunchKernelGGL(apply_kernel,  dim3(768),  dim3(256), 0, stream, P);
}